// Round 7
// baseline (1402.611 us; speedup 1.0000x reference)
//
#include <hip/hip_runtime.h>
#include <hip/hip_bf16.h>

typedef unsigned short u16;
typedef unsigned int   u32;

using bf16x8 = __attribute__((ext_vector_type(8))) short;
using f32x4  = __attribute__((ext_vector_type(4))) float;

constexpr int S = 4096, DIM = 4096, H = 32, HL = 8, D = 128;
constexpr int NQKV = (H + 2 * HL) * D;   // 6144
constexpr int QVW = (H + HL) * D;        // 5120: packed [Q | V] width
constexpr int TB = S / 8;                // 512 blocks of 8 tokens
constexpr int KL = 108;                  // 4 sink + 4 window + 100 heavy
constexpr float NEGF = -1e30f;
constexpr float SCALE = 0.08838834764831845f;  // 1/sqrt(128)

__device__ inline float bflo(u32 u) { return __builtin_bit_cast(float, u << 16); }
__device__ inline float bfhi(u32 u) { return __builtin_bit_cast(float, u & 0xFFFF0000u); }
__device__ inline u16 rne16(float f) {
  u32 b = __builtin_bit_cast(u32, f);
  return (u16)((b + 0x7FFFu + ((b >> 16) & 1u)) >> 16);
}
__device__ inline float bf2f(u16 h) { return __builtin_bit_cast(float, (u32)h << 16); }
__device__ inline u32 pk2(u16 a, u16 b) { return (u32)a | ((u32)b << 16); }

// async global->LDS, 16B per lane. LDS dest = wave-uniform base + lane*16.
__device__ __forceinline__ void gload16(const u16* g, u16* l) {
  __builtin_amdgcn_global_load_lds(
      (__attribute__((address_space(1))) void*)g,
      (__attribute__((address_space(3))) void*)l, 16, 0, 0);
}

// bijective XCD-aware swizzle of the flat workgroup id (nwg % 8 == 0).
__device__ inline void xcd_swz(int nx, int& bx, int& by) {
  const int flat = blockIdx.y * nx + blockIdx.x;
  const int nwg = nx * gridDim.y;
  const int cpx = nwg >> 3;
  const int s = (flat & 7) * cpx + (flat >> 3);
  bx = s % nx;
  by = s / nx;
}

// ================= conversion passes (memory-bound, one-shot) ===============
__global__ __launch_bounds__(256) void split_f32_kernel(
    const float* __restrict__ src, u16* __restrict__ hi, u16* __restrict__ lo) {
  const size_t i = ((size_t)blockIdx.x * 256 + threadIdx.x) * 8;
  float4 v0 = *(const float4*)(src + i);
  float4 v1 = *(const float4*)(src + i + 4);
  float f[8] = {v0.x, v0.y, v0.z, v0.w, v1.x, v1.y, v1.z, v1.w};
  u16 h[8], l[8];
#pragma unroll
  for (int j = 0; j < 8; ++j) {
    h[j] = rne16(f[j]);
    l[j] = rne16(f[j] - bf2f(h[j]));
  }
  uint4 ph, pl;
  ph.x = pk2(h[0], h[1]); ph.y = pk2(h[2], h[3]);
  ph.z = pk2(h[4], h[5]); ph.w = pk2(h[6], h[7]);
  pl.x = pk2(l[0], l[1]); pl.y = pk2(l[2], l[3]);
  pl.z = pk2(l[4], l[5]); pl.w = pk2(l[6], l[7]);
  *(uint4*)(hi + i) = ph;
  *(uint4*)(lo + i) = pl;
}

// wqkv f32 -> packed bf16 [Q rows | V rows] + K-head hi/lo separate buffers.
__global__ __launch_bounds__(256) void conv_wqkv_kernel(
    const float* __restrict__ src, u16* __restrict__ wqv,
    u16* __restrict__ wkh, u16* __restrict__ wkl) {
  const size_t i = ((size_t)blockIdx.x * 256 + threadIdx.x) * 8;
  float4 v0 = *(const float4*)(src + i);
  float4 v1 = *(const float4*)(src + i + 4);
  float f[8] = {v0.x, v0.y, v0.z, v0.w, v1.x, v1.y, v1.z, v1.w};
  u16 h[8];
#pragma unroll
  for (int j = 0; j < 8; ++j) h[j] = rne16(f[j]);
  uint4 ph;
  ph.x = pk2(h[0], h[1]); ph.y = pk2(h[2], h[3]);
  ph.z = pk2(h[4], h[5]); ph.w = pk2(h[6], h[7]);
  const int row = (int)(i >> 12);
  if (row < H * D) {                       // Q rows -> wqv[0..4095]
    *(uint4*)(wqv + i) = ph;
  } else if (row < (H + HL) * D) {         // K rows -> wkh/wkl
    const size_t off = i - (size_t)(H * D) * DIM;
    u16 l[8];
#pragma unroll
    for (int j = 0; j < 8; ++j) l[j] = rne16(f[j] - bf2f(h[j]));
    uint4 pl;
    pl.x = pk2(l[0], l[1]); pl.y = pk2(l[2], l[3]);
    pl.z = pk2(l[4], l[5]); pl.w = pk2(l[6], l[7]);
    *(uint4*)(wkh + off) = ph;
    *(uint4*)(wkl + off) = pl;
  } else {                                 // V rows -> wqv[4096..5119]
    *(uint4*)(wqv + (i - (size_t)(HL * D) * DIM)) = ph;
  }
}

__global__ __launch_bounds__(256) void cast_bf16_kernel(
    const float* __restrict__ src, u16* __restrict__ dst) {
  const size_t i = ((size_t)blockIdx.x * 256 + threadIdx.x) * 8;
  float4 v0 = *(const float4*)(src + i);
  float4 v1 = *(const float4*)(src + i + 4);
  uint4 ph;
  ph.x = pk2(rne16(v0.x), rne16(v0.y));
  ph.y = pk2(rne16(v0.z), rne16(v0.w));
  ph.z = pk2(rne16(v1.x), rne16(v1.y));
  ph.w = pk2(rne16(v1.z), rne16(v1.w));
  *(uint4*)(dst + i) = ph;
}

// ============ 8-phase 256x256 bf16 GEMM: C[M,N] = A[M,K] * B[N,K]^T =========
template <bool OBF16>
__global__ __launch_bounds__(512, 2) void gemm256(
    const u16* __restrict__ A, const u16* __restrict__ B,
    void* __restrict__ Cp, int M, int N, int K, int lda, int ldb, int ldc) {
  __shared__ u16 lds[4 * 16384];  // [buf][A|B][256*64]
  const int tid = threadIdx.x;
  const int w = tid >> 6, lane = tid & 63;
  const int wm = w >> 2, wn = w & 3;          // 2 x 4 wave grid
  const int l15 = lane & 15, g = lane >> 4;
  int bx, by;
  xcd_swz(gridDim.x, bx, by);
  const int m0 = by * 256, n0 = bx * 256;

  const u16* ga[4];
  const u16* gb[4];
#pragma unroll
  for (int r = 0; r < 4; ++r) {
    const int c = r * 512 + tid;
    const int row = c >> 3, j = c & 7;
    const int jsw = j ^ (row & 7);
    ga[r] = A + (size_t)(m0 + row) * lda + jsw * 8;
    gb[r] = B + (size_t)(n0 + row) * ldb + jsw * 8;
  }

  auto stageA = [&](int buf, int kt) {
    u16* base = lds + buf * 32768 + w * 512;
#pragma unroll
    for (int r = 0; r < 4; ++r) gload16(ga[r] + kt * 64, base + r * 4096);
  };
  auto stageB = [&](int buf, int kt) {
    u16* base = lds + buf * 32768 + 16384 + w * 512;
#pragma unroll
    for (int r = 0; r < 4; ++r) gload16(gb[r] + kt * 64, base + r * 4096);
  };

  bf16x8 afr[4][2], bfr[2][2];
  auto loadA = [&](int buf, int q) {
    const u16* Ab = lds + buf * 32768;
#pragma unroll
    for (int fr = 0; fr < 4; ++fr) {
      const int row = wm * 128 + q * 64 + fr * 16 + l15;
#pragma unroll
      for (int kh = 0; kh < 2; ++kh)
        afr[fr][kh] = *(const bf16x8*)(Ab + row * 64 + ((((kh << 2) | g)) ^ (l15 & 7)) * 8);
    }
  };
  auto loadB = [&](int buf, int r2) {
    const u16* Bb = lds + buf * 32768 + 16384;
#pragma unroll
    for (int fc = 0; fc < 2; ++fc) {
      const int row = wn * 64 + r2 * 32 + fc * 16 + l15;
#pragma unroll
      for (int kh = 0; kh < 2; ++kh)
        bfr[fc][kh] = *(const bf16x8*)(Bb + row * 64 + ((((kh << 2) | g)) ^ (l15 & 7)) * 8);
    }
  };

  f32x4 acc[8][4];
#pragma unroll
  for (int i = 0; i < 8; ++i)
#pragma unroll
    for (int j = 0; j < 4; ++j) acc[i][j] = {0.f, 0.f, 0.f, 0.f};

  auto mma = [&](int q, int r2) {
    __builtin_amdgcn_s_setprio(1);
#pragma unroll
    for (int fr = 0; fr < 4; ++fr)
#pragma unroll
      for (int fc = 0; fc < 2; ++fc)
#pragma unroll
        for (int kh = 0; kh < 2; ++kh)
          acc[q * 4 + fr][r2 * 2 + fc] = __builtin_amdgcn_mfma_f32_16x16x32_bf16(
              afr[fr][kh], bfr[fc][kh], acc[q * 4 + fr][r2 * 2 + fc], 0, 0, 0);
    __builtin_amdgcn_s_setprio(0);
  };

  stageA(0, 0);
  stageB(0, 0);
  const int NT = K / 64;
  for (int t = 0; t < NT; ++t) {
    const int cur = t & 1, nxt = cur ^ 1;
    if (t + 1 < NT) {
      stageA(nxt, t + 1);
      asm volatile("s_waitcnt vmcnt(4)" ::: "memory");
    } else {
      asm volatile("s_waitcnt vmcnt(0)" ::: "memory");
    }
    __builtin_amdgcn_sched_barrier(0);
    __builtin_amdgcn_s_barrier();
    loadA(cur, 0);
    loadB(cur, 0);
    mma(0, 0);
    __builtin_amdgcn_s_barrier();
    loadA(cur, 1);
    if (t + 1 < NT) stageB(nxt, t + 1);
    __builtin_amdgcn_s_barrier();
    mma(1, 0);
    __builtin_amdgcn_s_barrier();
    loadA(cur, 0);
    loadB(cur, 1);
    __builtin_amdgcn_s_barrier();
    mma(0, 1);
    __builtin_amdgcn_s_barrier();
    loadA(cur, 1);
    __builtin_amdgcn_s_barrier();
    mma(1, 1);
    __builtin_amdgcn_s_barrier();
  }
#pragma unroll
  for (int mf = 0; mf < 8; ++mf)
#pragma unroll
    for (int nf = 0; nf < 4; ++nf)
#pragma unroll
      for (int rg = 0; rg < 4; ++rg) {
        const int row = m0 + wm * 128 + mf * 16 + g * 4 + rg;
        const int col = n0 + wn * 64 + nf * 16 + l15;
        if constexpr (OBF16)
          ((u16*)Cp)[(size_t)row * ldc + col] = rne16(acc[mf][nf][rg]);
        else
          ((float*)Cp)[(size_t)row * ldc + col] = acc[mf][nf][rg];
      }
}

// ============ bf16 GEMM, 2-phase 128x128 (kept for the small V GEMM) ========
template <bool OBF16>
__global__ __launch_bounds__(256) void gemm_bf16(
    const u16* __restrict__ A, const u16* __restrict__ B,
    void* __restrict__ Cp, int M, int N, int K, int lda, int ldb, int ldc) {
  __shared__ u16 As[2][128 * 32];
  __shared__ u16 Bs[2][128 * 32];
  const int tid = threadIdx.x;
  const int lane = tid & 63;
  const int w = tid >> 6;
  const int wm = w >> 1, wn = w & 1;
  int bx, by;
  xcd_swz(gridDim.x, bx, by);
  const int m0 = by * 128, n0 = bx * 128;
  const int l15 = lane & 15, g = lane >> 4;
  const int srow = tid >> 2;          // 0..63
  const int scol = (tid & 3) * 8;     // u16 units: 0,8,16,24

  const u16* ga = A + (size_t)(m0 + srow) * lda + scol;
  const u16* gb = B + (size_t)(n0 + srow) * ldb + scol;
  const size_t a64 = (size_t)64 * lda;
  const size_t b64 = (size_t)64 * ldb;

  auto stage = [&](int buf, int k0) {
    u16* lA = As[buf] + w * 512;      // 1024 B per wave
    u16* lB = Bs[buf] + w * 512;
    gload16(ga + k0, lA);             // A rows 0..63
    gload16(ga + k0 + a64, lA + 2048);// A rows 64..127
    gload16(gb + k0, lB);             // B rows 0..63
    gload16(gb + k0 + b64, lB + 2048);// B rows 64..127
  };

  f32x4 acc[4][4];
#pragma unroll
  for (int i = 0; i < 4; ++i)
#pragma unroll
    for (int j = 0; j < 4; ++j) acc[i][j] = {0.f, 0.f, 0.f, 0.f};

  stage(0, 0);
  __syncthreads();
  const int niter = K / 32;
  for (int it = 0; it < niter; ++it) {
    const int cur = it & 1;
    if (it + 1 < niter) stage(cur ^ 1, (it + 1) * 32);  // prefetch in flight
    bf16x8 af[4], bfr[4];
#pragma unroll
    for (int i = 0; i < 4; ++i)
      af[i] = *(const bf16x8*)(As[cur] + (wm * 64 + i * 16 + l15) * 32 + g * 8);
#pragma unroll
    for (int j = 0; j < 4; ++j)
      bfr[j] = *(const bf16x8*)(Bs[cur] + (wn * 64 + j * 16 + l15) * 32 + g * 8);
#pragma unroll
    for (int i = 0; i < 4; ++i)
#pragma unroll
      for (int j = 0; j < 4; ++j)
        acc[i][j] = __builtin_amdgcn_mfma_f32_16x16x32_bf16(af[i], bfr[j], acc[i][j], 0, 0, 0);
    __syncthreads();  // drains prefetch (hidden behind MFMA) + barrier
  }
#pragma unroll
  for (int i = 0; i < 4; ++i)
#pragma unroll
    for (int j = 0; j < 4; ++j)
#pragma unroll
      for (int rg = 0; rg < 4; ++rg) {
        const int row = m0 + wm * 64 + i * 16 + g * 4 + rg;
        const int col = n0 + wn * 64 + j * 16 + l15;
        if constexpr (OBF16)
          ((u16*)Cp)[(size_t)row * ldc + col] = rne16(acc[i][j][rg]);
        else
          ((float*)Cp)[(size_t)row * ldc + col] = acc[i][j][rg];
      }
}

// ============ fused 3-term split GEMM: C = Al*Bh^T + Ah*Bl^T + Ah*Bh^T ======
__global__ __launch_bounds__(256) void gemm_k3(
    const u16* __restrict__ Ahg, const u16* __restrict__ Alg,
    const u16* __restrict__ Bhg, const u16* __restrict__ Blg,
    float* __restrict__ C, int M, int N, int K) {
  __shared__ u16 Ah[2][128 * 32];
  __shared__ u16 Al[2][128 * 32];
  __shared__ u16 Bh[2][64 * 32];
  __shared__ u16 Bl[2][64 * 32];
  const int tid = threadIdx.x;
  const int lane = tid & 63;
  const int w = tid >> 6;
  const int wm = w >> 1, wn = w & 1;   // wave tile: 64(M) x 32(N)
  int bx, by;
  xcd_swz(gridDim.x, bx, by);
  const int m0 = by * 128, n0 = bx * 64;
  const int l15 = lane & 15, g = lane >> 4;
  const int srow = tid >> 2;           // 0..63
  const int scol = (tid & 3) * 8;

  const u16* gah = Ahg + (size_t)(m0 + srow) * K + scol;
  const u16* gal = Alg + (size_t)(m0 + srow) * K + scol;
  const u16* gbh = Bhg + (size_t)(n0 + srow) * K + scol;
  const u16* gbl = Blg + (size_t)(n0 + srow) * K + scol;
  const size_t a64 = (size_t)64 * K;

  auto stage = [&](int buf, int k0) {
    gload16(gah + k0, Ah[buf] + w * 512);
    gload16(gah + k0 + a64, Ah[buf] + w * 512 + 2048);
    gload16(gal + k0, Al[buf] + w * 512);
    gload16(gal + k0 + a64, Al[buf] + w * 512 + 2048);
    gload16(gbh + k0, Bh[buf] + w * 512);
    gload16(gbl + k0, Bl[buf] + w * 512);
  };

  f32x4 acc[4][2];
#pragma unroll
  for (int i = 0; i < 4; ++i)
#pragma unroll
    for (int j = 0; j < 2; ++j) acc[i][j] = {0.f, 0.f, 0.f, 0.f};

  stage(0, 0);
  __syncthreads();
  const int niter = K / 32;
  for (int it = 0; it < niter; ++it) {
    const int cur = it & 1;
    if (it + 1 < niter) stage(cur ^ 1, (it + 1) * 32);
    bf16x8 fah[4], fal[4], fbh[2], fbl[2];
#pragma unroll
    for (int i = 0; i < 4; ++i) {
      fah[i] = *(const bf16x8*)(Ah[cur] + (wm * 64 + i * 16 + l15) * 32 + g * 8);
      fal[i] = *(const bf16x8*)(Al[cur] + (wm * 64 + i * 16 + l15) * 32 + g * 8);
    }
#pragma unroll
    for (int j = 0; j < 2; ++j) {
      fbh[j] = *(const bf16x8*)(Bh[cur] + (wn * 32 + j * 16 + l15) * 32 + g * 8);
      fbl[j] = *(const bf16x8*)(Bl[cur] + (wn * 32 + j * 16 + l15) * 32 + g * 8);
    }
#pragma unroll
    for (int i = 0; i < 4; ++i)
#pragma unroll
      for (int j = 0; j < 2; ++j) {
        acc[i][j] = __builtin_amdgcn_mfma_f32_16x16x32_bf16(fal[i], fbh[j], acc[i][j], 0, 0, 0);
        acc[i][j] = __builtin_amdgcn_mfma_f32_16x16x32_bf16(fah[i], fbl[j], acc[i][j], 0, 0, 0);
        acc[i][j] = __builtin_amdgcn_mfma_f32_16x16x32_bf16(fah[i], fbh[j], acc[i][j], 0, 0, 0);
      }
    __syncthreads();
  }
#pragma unroll
  for (int i = 0; i < 4; ++i)
#pragma unroll
    for (int j = 0; j < 2; ++j)
#pragma unroll
      for (int rg = 0; rg < 4; ++rg) {
        const int row = m0 + wm * 64 + i * 16 + g * 4 + rg;
        const int col = n0 + wn * 32 + j * 16 + l15;
        C[(size_t)row * N + col] = acc[i][j][rg];
      }
}

// ---------------- XC/XD: weighted token-sums of x (exact q_mean path) -------
__global__ __launch_bounds__(128) void xcd_kernel(
    const float* __restrict__ x, const float* __restrict__ freqs,
    float* __restrict__ XC, float* __restrict__ XD) {
  const int d = blockIdx.x * 128 + threadIdx.x;
  const int i0 = blockIdx.y * 32;
  const int s0 = blockIdx.z * 128;
  float accC[32], accD[32];
#pragma unroll
  for (int ii = 0; ii < 32; ++ii) { accC[ii] = 0.f; accD[ii] = 0.f; }
  for (int s = s0; s < s0 + 128; ++s) {
    const float xv = x[(size_t)s * DIM + d];
    const float* fr = freqs + (size_t)s * 128 + i0 * 2;  // block-uniform -> s_loads
#pragma unroll
    for (int ii = 0; ii < 32; ++ii) {
      accC[ii] += fr[2 * ii] * xv;
      accD[ii] += fr[2 * ii + 1] * xv;
    }
  }
#pragma unroll
  for (int ii = 0; ii < 32; ++ii) {
    atomicAdd(&XC[(size_t)(i0 + ii) * DIM + d], accC[ii]);
    atomicAdd(&XD[(size_t)(i0 + ii) * DIM + d], accD[ii]);
  }
}

// ---------------- M1/M2: per-q-row dots with XC/XD --------------------------
__global__ __launch_bounds__(256) void mrow_kernel(
    const float* __restrict__ wq, const float* __restrict__ XC,
    const float* __restrict__ XD, float* __restrict__ M1, float* __restrict__ M2) {
  const int r = blockIdx.x * 4 + (threadIdx.x >> 6);
  const int lane = threadIdx.x & 63;
  const int i = (r & 127) >> 1;
  const float* wr = wq + (size_t)r * DIM;
  const float* xc = XC + (size_t)i * DIM;
  const float* xd = XD + (size_t)i * DIM;
  float s1 = 0.f, s2 = 0.f;
  for (int k = lane; k < DIM; k += 64) {
    float wv = wr[k];
    s1 += wv * xc[k];
    s2 += wv * xd[k];
  }
#pragma unroll
  for (int off = 1; off < 64; off <<= 1) {
    s1 += __shfl_xor(s1, off, 64);
    s2 += __shfl_xor(s2, off, 64);
  }
  if (lane == 0) { M1[r] = s1; M2[r] = s2; }
}

// ---------------- RoPE on Q (bf16 in, bf16 out) -----------------------------
__global__ __launch_bounds__(256) void rope_q_kernel(
    const u16* __restrict__ qvb, const float* __restrict__ freqs,
    u16* __restrict__ qb) {
  const int h = blockIdx.y;
  const int s0 = blockIdx.x * 64;
  const int tid = threadIdx.x;
  const int d = tid & 127, half = tid >> 7;
  for (int pp = half; pp < 64; pp += 2) {
    const int s = s0 + pp;
    u32 pr = *(const u32*)(qvb + (size_t)s * QVW + h * D + (d & ~1));
    float a = bflo(pr), b = bfhi(pr);
    float2 fc = *(const float2*)(freqs + (size_t)s * 128 + (d & ~1));
    float o = (d & 1) ? (b * fc.x + a * fc.y) : (a * fc.x - b * fc.y);
    qb[((size_t)h * S + s) * D + d] = rne16(o);
  }
}

// ---------------- RoPE on precise K + block means; V cast + transpose -------
__global__ __launch_bounds__(128) void rope_kv_kernel(
    const float* __restrict__ kf, const u16* __restrict__ qvb,
    const float* __restrict__ freqs,
    u16* __restrict__ kb, u16* __restrict__ vbt, float* __restrict__ krep) {
  const int hl = blockIdx.y;
  const int t = blockIdx.x;  // token block 0..511
  const int d = threadIdx.x;
  float sum = 0.f;
  u16 vv[8];
#pragma unroll
  for (int pp = 0; pp < 8; ++pp) {
    const int s = t * 8 + pp;
    float2 kp = *(const float2*)(kf + (size_t)s * 1024 + hl * D + (d & ~1));
    float2 fc = *(const float2*)(freqs + (size_t)s * 128 + (d & ~1));
    float o = (d & 1) ? (kp.y * fc.x + kp.x * fc.y) : (kp.x * fc.x - kp.y * fc.y);
    kb[((size_t)hl * S + s) * D + d] = rne16(o);
    sum += o;
    vv[pp] = qvb[(size_t)s * QVW + H * D + hl * D + d];  // V at packed col 4096+
  }
  krep[((size_t)t * HL + hl) * D + d] = sum * 0.125f;
  uint4 pk;
  pk.x = pk2(vv[0], vv[1]);
  pk.y = pk2(vv[2], vv[3]);
  pk.z = pk2(vv[4], vv[5]);
  pk.w = pk2(vv[6], vv[7]);
  *(uint4*)(vbt + ((size_t)hl * D + d) * S + t * 8) = pk;
}

// ---------------- scores + top-100 selection per head -----------------------
__global__ __launch_bounds__(512) void topk_kernel(
    const float* __restrict__ M1, const float* __restrict__ M2,
    const float* __restrict__ krep, int* __restrict__ bidx) {
  const int h = blockIdx.x;
  const int t = threadIdx.x;  // block id 0..511
  __shared__ float qm[128];
  if (t < 128) {
    int r = h * 128 + t;
    float v = (t & 1) ? (M1[r] + M2[r - 1]) : (M1[r] - M2[r + 1]);
    qm[t] = v * (1.f / 4096.f);
  }
  __syncthreads();
  const float* kr = krep + ((size_t)t * HL + (h >> 2)) * 128;
  float s = 0.f;
#pragma unroll 8
  for (int d = 0; d < 128; ++d) s += qm[d] * kr[d];
  s *= SCALE;
  if (t < 4 || t >= 508) s = NEGF;  // sink + window masked out of top-k
  if (t < 4) {
    bidx[h * KL + t] = t;            // sink blocks 0..3
    bidx[h * KL + 4 + t] = 508 + t;  // window blocks 508..511
  }
  __shared__ float wv[8];
  __shared__ int wi[8];
  __shared__ int bestsh;
  for (int iter = 0; iter < 100; ++iter) {
    float v = s;
    int idx = t;
#pragma unroll
    for (int off = 1; off < 64; off <<= 1) {
      float ov = __shfl_xor(v, off, 64);
      int oi = __shfl_xor(idx, off, 64);
      if (ov > v || (ov == v && oi < idx)) { v = ov; idx = oi; }
    }
    if ((t & 63) == 0) { wv[t >> 6] = v; wi[t >> 6] = idx; }
    __syncthreads();
    if (t == 0) {
      float bv = wv[0];
      int bi = wi[0];
#pragma unroll
      for (int u = 1; u < 8; ++u)
        if (wv[u] > bv || (wv[u] == bv && wi[u] < bi)) { bv = wv[u]; bi = wi[u]; }
      bestsh = bi;
      bidx[h * KL + 8 + iter] = bi;
    }
    __syncthreads();
    if (t == bestsh) s = NEGF;
  }
}

// ---------------- MFMA flash attention over selected blocks -----------------
// 4 waves x 16 q-rows; KVBLK=64; XOR-swizzled LDS (T2, m214 recipe: chunk ^=
// row&7 on 256B/128B rows, both write+read); double-buffered K/V with
// async-STAGE split (T14: issue gathers at step top, ds_write to other buffer
// after QK -> latency hidden); ONE barrier per step; defer-max (T13).
// __launch_bounds__(256,2): VGPR cap 256 so staging regs don't spill (r5 bug).
__global__ __launch_bounds__(256, 2) void attn_mfma(
    const u16* __restrict__ qb, const u16* __restrict__ kb,
    const u16* __restrict__ vbt, const int* __restrict__ bidx,
    u16* __restrict__ attno) {
  __shared__ u16 Ks[2][64][128];  // [buf][tok][d]  (chunk-XOR swizzled)
  __shared__ u16 Vt[2][128][64];  // [buf][d][tok]  (chunk-XOR swizzled)
  __shared__ u16 Ps[4][16][64];   // per wave: [qrow][tok] (chunk-XOR swizzled)
  const int h = blockIdx.y, hl = h >> 2;
  const int q0 = blockIdx.x * 64;
  const int tid = threadIdx.x;
  const int w = tid >> 6, lane = tid & 63;
  const int l15 = lane & 15, g = lane >> 4;
  const int l7 = l15 & 7;
  constexpr int NS = (KL + 7) / 8;  // 14 (last step: 4 valid slots)

  bf16x8 qf[4];
  {
    const u16* qp = qb + ((size_t)h * S + q0 + w * 16 + l15) * D + g * 8;
#pragma unroll
    for (int c = 0; c < 4; ++c) qf[c] = *(const bf16x8*)(qp + c * 32);
  }
  f32x4 o[8];
#pragma unroll
  for (int c = 0; c < 8; ++c) o[c] = {0.f, 0.f, 0.f, 0.f};
  float mrow[4], lrow[4];
#pragma unroll
  for (int r = 0; r < 4; ++r) { mrow[r] = NEGF; lrow[r] = 0.f; }

  // staging roles
  const int ktok = tid >> 2, kq = tid & 3;  // K: token row 0..63, 64B segment
  const int kx = ktok & 7;
  const int vd = tid >> 1, vh = tid & 1;    // V: d row 0..127, 4-block half
  const int vx = vd & 7;

  uint4 kreg[4], vreg[4];  // live only from issue() to store() (across QK)

  auto issue = [&](int t8) {
    const int kslot = t8 + (ktok >> 3);
    const int kblk = (kslot < KL) ? bidx[h * KL + kslot] : 0;
    const u16* ksrc = kb + ((size_t)hl * S + kblk * 8 + (ktok & 7)) * D + kq * 32;
#pragma unroll
    for (int j = 0; j < 4; ++j) kreg[j] = *(const uint4*)(ksrc + j * 8);
    const u16* vsrc = vbt + ((size_t)hl * D + vd) * S;
#pragma unroll
    for (int j = 0; j < 4; ++j) {
      const int vslot = t8 + vh * 4 + j;
      const int vblk = (vslot < KL) ? bidx[h * KL + vslot] : 0;
      vreg[j] = *(const uint4*)(vsrc + (size_t)vblk * 8);
    }
  };
  auto store = [&](int buf) {
#pragma unroll
    for (int j = 0; j < 4; ++j)
      *(uint4*)&Ks[buf][ktok][((kq * 4 + j) ^ kx) * 8] = kreg[j];
#pragma unroll
    for (int j = 0; j < 4; ++j)
      *(uint4*)&Vt[buf][vd][((vh * 4 + j) ^ vx) * 8] = vreg[j];
  };

  // prologue: stage step 0 into buf 0
  issue(0);
  store(0);
  __syncthreads();

  for (int t = 0; t < NS; ++t) {
    const int cur = t & 1;
    const bool hasNext = (t + 1 < NS);
    // token bases for masking (uniform scalar loads)
    int tb[8];
#pragma unroll
    for (int s = 0; s < 8; ++s) {
      const int st = t * 8 + s;
      tb[s] = (st < KL) ? bidx[h * KL + st] * 8 : S + 8;
    }
    if (hasNext) issue((t + 1) * 8);  // HBM/L2 latency hides under QK

    // QK^T: 4 token-tiles x 4 d-chunks (swizzled reads: 2-way, free)
    f32x4 sT[4];
#pragma unroll
    for (int ti = 0; ti < 4; ++ti) sT[ti] = {0.f, 0.f, 0.f, 0.f};
#pragma unroll
    for (int c = 0; c < 4; ++c)
#pragma unroll
      for (int ti = 0; ti < 4; ++ti) {
        bf16x8 kf = *(const bf16x8*)&Ks[cur][ti * 16 + l15][((c * 4 + g) ^ l7) * 8];
        sT[ti] = __builtin_amdgcn_mfma_f32_16x16x32_bf16(qf[c], kf, sT[ti], 0, 0, 0);
      }

    if (hasNext) store(cur ^ 1);  // write next tile (vmcnt auto-waited here)

    // masks + per-row max
    int tg[4];
#pragma unroll
    for (int ti = 0; ti < 4; ++ti)
      tg[ti] = ((l15 & 8) ? tb[ti * 2 + 1] : tb[ti * 2]) + (l15 & 7);
    float p[4][4], mx[4];
#pragma unroll
    for (int r = 0; r < 4; ++r) {
      const int sq = q0 + w * 16 + g * 4 + r;
      float m = NEGF;
#pragma unroll
      for (int ti = 0; ti < 4; ++ti) {
        p[r][ti] = (tg[ti] <= sq) ? sT[ti][r] * SCALE : NEGF;
        m = fmaxf(m, p[r][ti]);
      }
      m = fmaxf(m, __shfl_xor(m, 1, 64));
      m = fmaxf(m, __shfl_xor(m, 2, 64));
      m = fmaxf(m, __shfl_xor(m, 4, 64));
      m = fmaxf(m, __shfl_xor(m, 8, 64));
      mx[r] = m;
    }
    // defer-max: rescale only if some row's max grew past THR=8
    const bool need = (mx[0] > mrow[0] + 8.f) | (mx[1] > mrow[1] + 8.f) |
                      (mx[2] > mrow[2] + 8.f) | (mx[3] > mrow[3] + 8.f);
    if (__any((int)need)) {
#pragma unroll
      for (int r = 0; r < 4; ++r) {
        const float mnew = fmaxf(mrow[r], mx[r]);
        const float alpha = __expf(mrow[r] - mnew);
        mrow[r] = mnew;
        lrow[r] *= alpha;
#pragma unroll
        for (int c = 0; c < 8; ++c) o[c][r] *= alpha;
      }
    }
    // exp + row-sum + P store (bounded by e^8 under defer)
#pragma unroll
    for (int r = 0; r < 4; ++r) {
      float rs = 0.f;
#pragma unroll
      for (int ti = 0; ti < 4; ++ti) {
        p[r][ti] = __expf(p[r][ti] - mrow[r]);
        rs += p[r][ti];
      }
      rs += __shfl_xor(rs, 1, 64);
      rs += __shfl_xor(rs, 2, 64);
      rs += __shfl_xor(rs, 4, 64);
      rs += __shfl_xor(rs, 8, 64);
      lrow[r] += rs;
      const int prow = g * 4 + r;
      const int px = prow & 7;
#pragma unroll
      for (int ti = 0; ti < 4; ++ti) {
        const int ch = ti * 2 + (l15 >> 3);          // logical 8-elem chunk
        Ps[w][prow][((ch ^ px) * 8) + l7] = rne16(p[r][ti]);
      }
    }
    // PV: K=64 via two 32-token chunks (swizzled reads)
    bf16x8 pf0 = *(const bf16x8*)&Ps[w][l15][(g ^ l7) * 8];
    bf16x8 pf1 = *(const bf16x8*)&Ps[w][l15][((4 + g) ^ l7) * 8];
#pragma unroll
    for (int c = 0; c < 8; ++c) {
      const int vrow = c * 16 + l15;
      bf16x8 v0 = *(const bf16x8*)&Vt[cur][vrow][(g ^ l7) * 8];
      bf16x8 v1 = *(const bf16x8*)&Vt[cur][vrow][((4 + g) ^ l7) * 8];
      o[c] = __builtin_amdgcn_mfma_f32_16x16x32_bf16(pf0, v0, o[c], 0, 0, 0);
      o[c] = __builtin_amdgcn_mfma_f32_16x16x32_bf16(pf1, v1, o[c], 0, 0, 0);
    }
    __syncthreads();  // single barrier/step: cur reads done + nxt writes visible
  }
  float inv[4];
#pragma unroll
  for (int r = 0; r < 4; ++r) inv[r] = 1.f / lrow[r];
#pragma unroll
  for (int c = 0; c < 8; ++c)
#pragma unroll
    for (int r = 0; r < 4; ++r)
      attno[(size_t)(q0 + w * 16 + g * 4 + r) * DIM + h * D + c * 16 + l15] =
          rne16(o[c][r] * inv[r]);
}

extern "C" void kernel_launch(void* const* d_in, const int* in_sizes, int n_in,
                              void* d_out, int out_size, void* d_ws, size_t ws_size,
                              hipStream_t stream) {
  const float* x     = (const float*)d_in[0];  // (1,4096,4096)
  const float* freqs = (const float*)d_in[1];  // (4096,64,2)
  const float* wqkv  = (const float*)d_in[2];  // (6144,4096)
  const float* wo    = (const float*)d_in[3];  // (4096,4096)
  float* out = (float*)d_out;                  // (1,4096,4096) f32

  char* p = (char*)d_ws;
  auto alloc = [&](size_t bytes) {
    char* r = p;
    p += (bytes + 255) & ~(size_t)255;
    return r;
  };
  u16*   xh   = (u16*)alloc((size_t)S * DIM * 2);        // 32 MB x hi (rne bf16)
  u16*   xl   = (u16*)alloc((size_t)S * DIM * 2);        // 32 MB x lo residual
  u16*   wqv  = (u16*)alloc((size_t)QVW * DIM * 2);      // 40 MB packed [Q|V] bf16
  u16*   wkh  = (u16*)alloc((size_t)HL * D * DIM * 2);   //  8 MB K-head hi
  u16*   wkl  = (u16*)alloc((size_t)HL * D * DIM * 2);   //  8 MB K-head lo
  u16*   wob  = (u16*)alloc((size_t)DIM * DIM * 2);      // 32 MB wo bf16
  u16*   qvb  = (u16*)alloc((size_t)S * QVW * 2);        // 40 MB bf16 [Q|V]
  float* kf32 = (float*)alloc((size_t)S * HL * D * 4);   // 16 MB precise k
  u16*   qb   = (u16*)alloc((size_t)H * S * D * 2);      // 32 MB (H,S,D)
  u16*   kb   = (u16*)alloc((size_t)HL * S * D * 2);     //  8 MB (HL,S,D)
  u16*   vbt  = (u16*)alloc((size_t)HL * D * S * 2);     //  8 MB (HL,D,S)
  float* krep = (float*)alloc((size_t)TB * HL * D * 4);  //  2 MB
  float* XC   = (float*)alloc((size_t)64 * DIM * 4);     //  1 MB
  float* XD   = (float*)alloc((size_t)64 * DIM * 4);     //  1 MB
  float* M1   = (float*)alloc((size_t)H * D * 4);
  float* M2   = (float*)alloc((size_t)H * D * 4);
  int*   bidx = (int*)alloc((size_t)H * KL * 4);
  u16*   attno = (u16*)alloc((size_t)S * DIM * 2);       // 32 MB

  hipMemsetAsync(XC, 0, (size_t)64 * DIM * 4, stream);
  hipMemsetAsync(XD, 0, (size_t)64 * DIM * 4, stream);

  // ---- conversion passes (memory-bound) ----
  split_f32_kernel<<<(S * DIM) / 2048, 256, 0, stream>>>(x, xh, xl);
  conv_wqkv_kernel<<<(NQKV * DIM) / 2048, 256, 0, stream>>>(wqkv, wqv, wkh, wkl);
  cast_bf16_kernel<<<(DIM * DIM) / 2048, 256, 0, stream>>>(wo, wob);

  // ---- bf16 Q (8-phase 256^2; grid 256 = 1 block/CU) ----
  gemm256<true><<<dim3((H * D) / 256, S / 256), 512, 0, stream>>>(
      xh, wqv, qvb, S, H * D, DIM, DIM, DIM, QVW);
  // ---- bf16 V (2-phase 128^2; N=1024, grid 256) ----
  gemm_bf16<true><<<dim3((HL * D) / 128, S / 128), 256, 0, stream>>>(
      xh, wqv + (size_t)(H * D) * DIM, qvb + H * D, S, HL * D, DIM, DIM, DIM, QVW);

  // ---- precise K heads: fused (Al*Bh + Ah*Bl + Ah*Bh), single pass ----
  gemm_k3<<<dim3((HL * D) / 64, S / 128), 256, 0, stream>>>(
      xh, xl, wkh, wkl, kf32, S, HL * D, DIM);

  // ---- exact q_mean via rope linearity (f32 inputs, unchanged) ----
  xcd_kernel<<<dim3(32, 2, 32), 128, 0, stream>>>(x, freqs, XC, XD);
  mrow_kernel<<<1024, 256, 0, stream>>>(wqkv, XC, XD, M1, M2);
  rope_q_kernel<<<dim3(S / 64, H), 256, 0, stream>>>(qvb, freqs, qb);
  rope_kv_kernel<<<dim3(TB, HL), 128, 0, stream>>>(kf32, qvb, freqs, kb, vbt, krep);
  topk_kernel<<<H, 512, 0, stream>>>(M1, M2, krep, bidx);
  attn_mfma<<<dim3(S / 64, H), 256, 0, stream>>>(qb, kb, vbt, bidx, attno);
  // ---- output projection (8-phase 256^2; grid 256) ----
  gemm256<false><<<dim3(DIM / 256, S / 256), 512, 0, stream>>>(
      attno, wob, out, S, DIM, DIM, DIM, DIM, DIM);
}

// Round 8
// 1294.947 us; speedup vs baseline: 1.0831x; 1.0831x over previous
//
#include <hip/hip_runtime.h>
#include <hip/hip_bf16.h>

typedef unsigned short u16;
typedef unsigned int   u32;

using bf16x8 = __attribute__((ext_vector_type(8))) short;
using f32x4  = __attribute__((ext_vector_type(4))) float;

constexpr int S = 4096, DIM = 4096, H = 32, HL = 8, D = 128;
constexpr int NQKV = (H + 2 * HL) * D;   // 6144
constexpr int QVW = (H + HL) * D;        // 5120: packed [Q | V] width
constexpr int TB = S / 8;                // 512 blocks of 8 tokens
constexpr int KL = 108;                  // 4 sink + 4 window + 100 heavy
constexpr float NEGF = -1e30f;
constexpr float SCALE = 0.08838834764831845f;  // 1/sqrt(128)

__device__ inline float bflo(u32 u) { return __builtin_bit_cast(float, u << 16); }
__device__ inline float bfhi(u32 u) { return __builtin_bit_cast(float, u & 0xFFFF0000u); }
__device__ inline u16 rne16(float f) {
  u32 b = __builtin_bit_cast(u32, f);
  return (u16)((b + 0x7FFFu + ((b >> 16) & 1u)) >> 16);
}
__device__ inline float bf2f(u16 h) { return __builtin_bit_cast(float, (u32)h << 16); }
__device__ inline u32 pk2(u16 a, u16 b) { return (u32)a | ((u32)b << 16); }

// async global->LDS, 16B per lane. LDS dest = wave-uniform base + lane*16.
__device__ __forceinline__ void gload16(const u16* g, u16* l) {
  __builtin_amdgcn_global_load_lds(
      (__attribute__((address_space(1))) void*)g,
      (__attribute__((address_space(3))) void*)l, 16, 0, 0);
}

// bijective XCD-aware swizzle of the flat workgroup id (nwg % 8 == 0).
__device__ inline void xcd_swz(int nx, int& bx, int& by) {
  const int flat = blockIdx.y * nx + blockIdx.x;
  const int nwg = nx * gridDim.y;
  const int cpx = nwg >> 3;
  const int s = (flat & 7) * cpx + (flat >> 3);
  bx = s % nx;
  by = s / nx;
}

// ================= conversion passes (memory-bound, one-shot) ===============
__global__ __launch_bounds__(256) void split_f32_kernel(
    const float* __restrict__ src, u16* __restrict__ hi, u16* __restrict__ lo) {
  const size_t i = ((size_t)blockIdx.x * 256 + threadIdx.x) * 8;
  float4 v0 = *(const float4*)(src + i);
  float4 v1 = *(const float4*)(src + i + 4);
  float f[8] = {v0.x, v0.y, v0.z, v0.w, v1.x, v1.y, v1.z, v1.w};
  u16 h[8], l[8];
#pragma unroll
  for (int j = 0; j < 8; ++j) {
    h[j] = rne16(f[j]);
    l[j] = rne16(f[j] - bf2f(h[j]));
  }
  uint4 ph, pl;
  ph.x = pk2(h[0], h[1]); ph.y = pk2(h[2], h[3]);
  ph.z = pk2(h[4], h[5]); ph.w = pk2(h[6], h[7]);
  pl.x = pk2(l[0], l[1]); pl.y = pk2(l[2], l[3]);
  pl.z = pk2(l[4], l[5]); pl.w = pk2(l[6], l[7]);
  *(uint4*)(hi + i) = ph;
  *(uint4*)(lo + i) = pl;
}

// wqkv f32 -> packed bf16 [Q rows | V rows] + K-head hi/lo separate buffers.
__global__ __launch_bounds__(256) void conv_wqkv_kernel(
    const float* __restrict__ src, u16* __restrict__ wqv,
    u16* __restrict__ wkh, u16* __restrict__ wkl) {
  const size_t i = ((size_t)blockIdx.x * 256 + threadIdx.x) * 8;
  float4 v0 = *(const float4*)(src + i);
  float4 v1 = *(const float4*)(src + i + 4);
  float f[8] = {v0.x, v0.y, v0.z, v0.w, v1.x, v1.y, v1.z, v1.w};
  u16 h[8];
#pragma unroll
  for (int j = 0; j < 8; ++j) h[j] = rne16(f[j]);
  uint4 ph;
  ph.x = pk2(h[0], h[1]); ph.y = pk2(h[2], h[3]);
  ph.z = pk2(h[4], h[5]); ph.w = pk2(h[6], h[7]);
  const int row = (int)(i >> 12);
  if (row < H * D) {                       // Q rows -> wqv[0..4095]
    *(uint4*)(wqv + i) = ph;
  } else if (row < (H + HL) * D) {         // K rows -> wkh/wkl
    const size_t off = i - (size_t)(H * D) * DIM;
    u16 l[8];
#pragma unroll
    for (int j = 0; j < 8; ++j) l[j] = rne16(f[j] - bf2f(h[j]));
    uint4 pl;
    pl.x = pk2(l[0], l[1]); pl.y = pk2(l[2], l[3]);
    pl.z = pk2(l[4], l[5]); pl.w = pk2(l[6], l[7]);
    *(uint4*)(wkh + off) = ph;
    *(uint4*)(wkl + off) = pl;
  } else {                                 // V rows -> wqv[4096..5119]
    *(uint4*)(wqv + (i - (size_t)(HL * D) * DIM)) = ph;
  }
}

__global__ __launch_bounds__(256) void cast_bf16_kernel(
    const float* __restrict__ src, u16* __restrict__ dst) {
  const size_t i = ((size_t)blockIdx.x * 256 + threadIdx.x) * 8;
  float4 v0 = *(const float4*)(src + i);
  float4 v1 = *(const float4*)(src + i + 4);
  uint4 ph;
  ph.x = pk2(rne16(v0.x), rne16(v0.y));
  ph.y = pk2(rne16(v0.z), rne16(v0.w));
  ph.z = pk2(rne16(v1.x), rne16(v1.y));
  ph.w = pk2(rne16(v1.z), rne16(v1.w));
  *(uint4*)(dst + i) = ph;
}

// ============ 8-phase 256x256 bf16 GEMM: C[M,N] = A[M,K] * B[N,K]^T =========
template <bool OBF16>
__global__ __launch_bounds__(512, 2) void gemm256(
    const u16* __restrict__ A, const u16* __restrict__ B,
    void* __restrict__ Cp, int M, int N, int K, int lda, int ldb, int ldc) {
  __shared__ u16 lds[4 * 16384];  // [buf][A|B][256*64]
  const int tid = threadIdx.x;
  const int w = tid >> 6, lane = tid & 63;
  const int wm = w >> 2, wn = w & 3;          // 2 x 4 wave grid
  const int l15 = lane & 15, g = lane >> 4;
  int bx, by;
  xcd_swz(gridDim.x, bx, by);
  const int m0 = by * 256, n0 = bx * 256;

  const u16* ga[4];
  const u16* gb[4];
#pragma unroll
  for (int r = 0; r < 4; ++r) {
    const int c = r * 512 + tid;
    const int row = c >> 3, j = c & 7;
    const int jsw = j ^ (row & 7);
    ga[r] = A + (size_t)(m0 + row) * lda + jsw * 8;
    gb[r] = B + (size_t)(n0 + row) * ldb + jsw * 8;
  }

  auto stageA = [&](int buf, int kt) {
    u16* base = lds + buf * 32768 + w * 512;
#pragma unroll
    for (int r = 0; r < 4; ++r) gload16(ga[r] + kt * 64, base + r * 4096);
  };
  auto stageB = [&](int buf, int kt) {
    u16* base = lds + buf * 32768 + 16384 + w * 512;
#pragma unroll
    for (int r = 0; r < 4; ++r) gload16(gb[r] + kt * 64, base + r * 4096);
  };

  bf16x8 afr[4][2], bfr[2][2];
  auto loadA = [&](int buf, int q) {
    const u16* Ab = lds + buf * 32768;
#pragma unroll
    for (int fr = 0; fr < 4; ++fr) {
      const int row = wm * 128 + q * 64 + fr * 16 + l15;
#pragma unroll
      for (int kh = 0; kh < 2; ++kh)
        afr[fr][kh] = *(const bf16x8*)(Ab + row * 64 + ((((kh << 2) | g)) ^ (l15 & 7)) * 8);
    }
  };
  auto loadB = [&](int buf, int r2) {
    const u16* Bb = lds + buf * 32768 + 16384;
#pragma unroll
    for (int fc = 0; fc < 2; ++fc) {
      const int row = wn * 64 + r2 * 32 + fc * 16 + l15;
#pragma unroll
      for (int kh = 0; kh < 2; ++kh)
        bfr[fc][kh] = *(const bf16x8*)(Bb + row * 64 + ((((kh << 2) | g)) ^ (l15 & 7)) * 8);
    }
  };

  f32x4 acc[8][4];
#pragma unroll
  for (int i = 0; i < 8; ++i)
#pragma unroll
    for (int j = 0; j < 4; ++j) acc[i][j] = {0.f, 0.f, 0.f, 0.f};

  auto mma = [&](int q, int r2) {
    __builtin_amdgcn_s_setprio(1);
#pragma unroll
    for (int fr = 0; fr < 4; ++fr)
#pragma unroll
      for (int fc = 0; fc < 2; ++fc)
#pragma unroll
        for (int kh = 0; kh < 2; ++kh)
          acc[q * 4 + fr][r2 * 2 + fc] = __builtin_amdgcn_mfma_f32_16x16x32_bf16(
              afr[fr][kh], bfr[fc][kh], acc[q * 4 + fr][r2 * 2 + fc], 0, 0, 0);
    __builtin_amdgcn_s_setprio(0);
  };

  stageA(0, 0);
  stageB(0, 0);
  const int NT = K / 64;
  for (int t = 0; t < NT; ++t) {
    const int cur = t & 1, nxt = cur ^ 1;
    if (t + 1 < NT) {
      stageA(nxt, t + 1);
      asm volatile("s_waitcnt vmcnt(4)" ::: "memory");
    } else {
      asm volatile("s_waitcnt vmcnt(0)" ::: "memory");
    }
    __builtin_amdgcn_sched_barrier(0);
    __builtin_amdgcn_s_barrier();
    loadA(cur, 0);
    loadB(cur, 0);
    mma(0, 0);
    __builtin_amdgcn_s_barrier();
    loadA(cur, 1);
    if (t + 1 < NT) stageB(nxt, t + 1);
    __builtin_amdgcn_s_barrier();
    mma(1, 0);
    __builtin_amdgcn_s_barrier();
    loadA(cur, 0);
    loadB(cur, 1);
    __builtin_amdgcn_s_barrier();
    mma(0, 1);
    __builtin_amdgcn_s_barrier();
    loadA(cur, 1);
    __builtin_amdgcn_s_barrier();
    mma(1, 1);
    __builtin_amdgcn_s_barrier();
  }
#pragma unroll
  for (int mf = 0; mf < 8; ++mf)
#pragma unroll
    for (int nf = 0; nf < 4; ++nf)
#pragma unroll
      for (int rg = 0; rg < 4; ++rg) {
        const int row = m0 + wm * 128 + mf * 16 + g * 4 + rg;
        const int col = n0 + wn * 64 + nf * 16 + l15;
        if constexpr (OBF16)
          ((u16*)Cp)[(size_t)row * ldc + col] = rne16(acc[mf][nf][rg]);
        else
          ((float*)Cp)[(size_t)row * ldc + col] = acc[mf][nf][rg];
      }
}

// ============ bf16 GEMM, 2-phase 128x128 (kept for the small V GEMM) ========
template <bool OBF16>
__global__ __launch_bounds__(256) void gemm_bf16(
    const u16* __restrict__ A, const u16* __restrict__ B,
    void* __restrict__ Cp, int M, int N, int K, int lda, int ldb, int ldc) {
  __shared__ u16 As[2][128 * 32];
  __shared__ u16 Bs[2][128 * 32];
  const int tid = threadIdx.x;
  const int lane = tid & 63;
  const int w = tid >> 6;
  const int wm = w >> 1, wn = w & 1;
  int bx, by;
  xcd_swz(gridDim.x, bx, by);
  const int m0 = by * 128, n0 = bx * 128;
  const int l15 = lane & 15, g = lane >> 4;
  const int srow = tid >> 2;          // 0..63
  const int scol = (tid & 3) * 8;     // u16 units: 0,8,16,24

  const u16* ga = A + (size_t)(m0 + srow) * lda + scol;
  const u16* gb = B + (size_t)(n0 + srow) * ldb + scol;
  const size_t a64 = (size_t)64 * lda;
  const size_t b64 = (size_t)64 * ldb;

  auto stage = [&](int buf, int k0) {
    u16* lA = As[buf] + w * 512;      // 1024 B per wave
    u16* lB = Bs[buf] + w * 512;
    gload16(ga + k0, lA);             // A rows 0..63
    gload16(ga + k0 + a64, lA + 2048);// A rows 64..127
    gload16(gb + k0, lB);             // B rows 0..63
    gload16(gb + k0 + b64, lB + 2048);// B rows 64..127
  };

  f32x4 acc[4][4];
#pragma unroll
  for (int i = 0; i < 4; ++i)
#pragma unroll
    for (int j = 0; j < 4; ++j) acc[i][j] = {0.f, 0.f, 0.f, 0.f};

  stage(0, 0);
  __syncthreads();
  const int niter = K / 32;
  for (int it = 0; it < niter; ++it) {
    const int cur = it & 1;
    if (it + 1 < niter) stage(cur ^ 1, (it + 1) * 32);  // prefetch in flight
    bf16x8 af[4], bfr[4];
#pragma unroll
    for (int i = 0; i < 4; ++i)
      af[i] = *(const bf16x8*)(As[cur] + (wm * 64 + i * 16 + l15) * 32 + g * 8);
#pragma unroll
    for (int j = 0; j < 4; ++j)
      bfr[j] = *(const bf16x8*)(Bs[cur] + (wn * 64 + j * 16 + l15) * 32 + g * 8);
#pragma unroll
    for (int i = 0; i < 4; ++i)
#pragma unroll
      for (int j = 0; j < 4; ++j)
        acc[i][j] = __builtin_amdgcn_mfma_f32_16x16x32_bf16(af[i], bfr[j], acc[i][j], 0, 0, 0);
    __syncthreads();  // drains prefetch (hidden behind MFMA) + barrier
  }
#pragma unroll
  for (int i = 0; i < 4; ++i)
#pragma unroll
    for (int j = 0; j < 4; ++j)
#pragma unroll
      for (int rg = 0; rg < 4; ++rg) {
        const int row = m0 + wm * 64 + i * 16 + g * 4 + rg;
        const int col = n0 + wn * 64 + j * 16 + l15;
        if constexpr (OBF16)
          ((u16*)Cp)[(size_t)row * ldc + col] = rne16(acc[i][j][rg]);
        else
          ((float*)Cp)[(size_t)row * ldc + col] = acc[i][j][rg];
      }
}

// ============ fused 3-term split GEMM: C = Al*Bh^T + Ah*Bl^T + Ah*Bh^T ======
__global__ __launch_bounds__(256) void gemm_k3(
    const u16* __restrict__ Ahg, const u16* __restrict__ Alg,
    const u16* __restrict__ Bhg, const u16* __restrict__ Blg,
    float* __restrict__ C, int M, int N, int K) {
  __shared__ u16 Ah[2][128 * 32];
  __shared__ u16 Al[2][128 * 32];
  __shared__ u16 Bh[2][64 * 32];
  __shared__ u16 Bl[2][64 * 32];
  const int tid = threadIdx.x;
  const int lane = tid & 63;
  const int w = tid >> 6;
  const int wm = w >> 1, wn = w & 1;   // wave tile: 64(M) x 32(N)
  int bx, by;
  xcd_swz(gridDim.x, bx, by);
  const int m0 = by * 128, n0 = bx * 64;
  const int l15 = lane & 15, g = lane >> 4;
  const int srow = tid >> 2;           // 0..63
  const int scol = (tid & 3) * 8;

  const u16* gah = Ahg + (size_t)(m0 + srow) * K + scol;
  const u16* gal = Alg + (size_t)(m0 + srow) * K + scol;
  const u16* gbh = Bhg + (size_t)(n0 + srow) * K + scol;
  const u16* gbl = Blg + (size_t)(n0 + srow) * K + scol;
  const size_t a64 = (size_t)64 * K;

  auto stage = [&](int buf, int k0) {
    gload16(gah + k0, Ah[buf] + w * 512);
    gload16(gah + k0 + a64, Ah[buf] + w * 512 + 2048);
    gload16(gal + k0, Al[buf] + w * 512);
    gload16(gal + k0 + a64, Al[buf] + w * 512 + 2048);
    gload16(gbh + k0, Bh[buf] + w * 512);
    gload16(gbl + k0, Bl[buf] + w * 512);
  };

  f32x4 acc[4][2];
#pragma unroll
  for (int i = 0; i < 4; ++i)
#pragma unroll
    for (int j = 0; j < 2; ++j) acc[i][j] = {0.f, 0.f, 0.f, 0.f};

  stage(0, 0);
  __syncthreads();
  const int niter = K / 32;
  for (int it = 0; it < niter; ++it) {
    const int cur = it & 1;
    if (it + 1 < niter) stage(cur ^ 1, (it + 1) * 32);
    bf16x8 fah[4], fal[4], fbh[2], fbl[2];
#pragma unroll
    for (int i = 0; i < 4; ++i) {
      fah[i] = *(const bf16x8*)(Ah[cur] + (wm * 64 + i * 16 + l15) * 32 + g * 8);
      fal[i] = *(const bf16x8*)(Al[cur] + (wm * 64 + i * 16 + l15) * 32 + g * 8);
    }
#pragma unroll
    for (int j = 0; j < 2; ++j) {
      fbh[j] = *(const bf16x8*)(Bh[cur] + (wn * 32 + j * 16 + l15) * 32 + g * 8);
      fbl[j] = *(const bf16x8*)(Bl[cur] + (wn * 32 + j * 16 + l15) * 32 + g * 8);
    }
#pragma unroll
    for (int i = 0; i < 4; ++i)
#pragma unroll
      for (int j = 0; j < 2; ++j) {
        acc[i][j] = __builtin_amdgcn_mfma_f32_16x16x32_bf16(fal[i], fbh[j], acc[i][j], 0, 0, 0);
        acc[i][j] = __builtin_amdgcn_mfma_f32_16x16x32_bf16(fah[i], fbl[j], acc[i][j], 0, 0, 0);
        acc[i][j] = __builtin_amdgcn_mfma_f32_16x16x32_bf16(fah[i], fbh[j], acc[i][j], 0, 0, 0);
      }
    __syncthreads();
  }
#pragma unroll
  for (int i = 0; i < 4; ++i)
#pragma unroll
    for (int j = 0; j < 2; ++j)
#pragma unroll
      for (int rg = 0; rg < 4; ++rg) {
        const int row = m0 + wm * 64 + i * 16 + g * 4 + rg;
        const int col = n0 + wn * 32 + j * 16 + l15;
        C[(size_t)row * N + col] = acc[i][j][rg];
      }
}

// ---------------- XC/XD: weighted token-sums of x (exact q_mean path) -------
__global__ __launch_bounds__(128) void xcd_kernel(
    const float* __restrict__ x, const float* __restrict__ freqs,
    float* __restrict__ XC, float* __restrict__ XD) {
  const int d = blockIdx.x * 128 + threadIdx.x;
  const int i0 = blockIdx.y * 32;
  const int s0 = blockIdx.z * 128;
  float accC[32], accD[32];
#pragma unroll
  for (int ii = 0; ii < 32; ++ii) { accC[ii] = 0.f; accD[ii] = 0.f; }
  for (int s = s0; s < s0 + 128; ++s) {
    const float xv = x[(size_t)s * DIM + d];
    const float* fr = freqs + (size_t)s * 128 + i0 * 2;  // block-uniform -> s_loads
#pragma unroll
    for (int ii = 0; ii < 32; ++ii) {
      accC[ii] += fr[2 * ii] * xv;
      accD[ii] += fr[2 * ii + 1] * xv;
    }
  }
#pragma unroll
  for (int ii = 0; ii < 32; ++ii) {
    atomicAdd(&XC[(size_t)(i0 + ii) * DIM + d], accC[ii]);
    atomicAdd(&XD[(size_t)(i0 + ii) * DIM + d], accD[ii]);
  }
}

// ---------------- M1/M2: per-q-row dots with XC/XD --------------------------
__global__ __launch_bounds__(256) void mrow_kernel(
    const float* __restrict__ wq, const float* __restrict__ XC,
    const float* __restrict__ XD, float* __restrict__ M1, float* __restrict__ M2) {
  const int r = blockIdx.x * 4 + (threadIdx.x >> 6);
  const int lane = threadIdx.x & 63;
  const int i = (r & 127) >> 1;
  const float* wr = wq + (size_t)r * DIM;
  const float* xc = XC + (size_t)i * DIM;
  const float* xd = XD + (size_t)i * DIM;
  float s1 = 0.f, s2 = 0.f;
  for (int k = lane; k < DIM; k += 64) {
    float wv = wr[k];
    s1 += wv * xc[k];
    s2 += wv * xd[k];
  }
#pragma unroll
  for (int off = 1; off < 64; off <<= 1) {
    s1 += __shfl_xor(s1, off, 64);
    s2 += __shfl_xor(s2, off, 64);
  }
  if (lane == 0) { M1[r] = s1; M2[r] = s2; }
}

// ---------------- RoPE on Q (bf16 in, bf16 out) -----------------------------
__global__ __launch_bounds__(256) void rope_q_kernel(
    const u16* __restrict__ qvb, const float* __restrict__ freqs,
    u16* __restrict__ qb) {
  const int h = blockIdx.y;
  const int s0 = blockIdx.x * 64;
  const int tid = threadIdx.x;
  const int d = tid & 127, half = tid >> 7;
  for (int pp = half; pp < 64; pp += 2) {
    const int s = s0 + pp;
    u32 pr = *(const u32*)(qvb + (size_t)s * QVW + h * D + (d & ~1));
    float a = bflo(pr), b = bfhi(pr);
    float2 fc = *(const float2*)(freqs + (size_t)s * 128 + (d & ~1));
    float o = (d & 1) ? (b * fc.x + a * fc.y) : (a * fc.x - b * fc.y);
    qb[((size_t)h * S + s) * D + d] = rne16(o);
  }
}

// ---------------- RoPE on precise K + block means; V cast + transpose -------
__global__ __launch_bounds__(128) void rope_kv_kernel(
    const float* __restrict__ kf, const u16* __restrict__ qvb,
    const float* __restrict__ freqs,
    u16* __restrict__ kb, u16* __restrict__ vbt, float* __restrict__ krep) {
  const int hl = blockIdx.y;
  const int t = blockIdx.x;  // token block 0..511
  const int d = threadIdx.x;
  float sum = 0.f;
  u16 vv[8];
#pragma unroll
  for (int pp = 0; pp < 8; ++pp) {
    const int s = t * 8 + pp;
    float2 kp = *(const float2*)(kf + (size_t)s * 1024 + hl * D + (d & ~1));
    float2 fc = *(const float2*)(freqs + (size_t)s * 128 + (d & ~1));
    float o = (d & 1) ? (kp.y * fc.x + kp.x * fc.y) : (kp.x * fc.x - kp.y * fc.y);
    kb[((size_t)hl * S + s) * D + d] = rne16(o);
    sum += o;
    vv[pp] = qvb[(size_t)s * QVW + H * D + hl * D + d];  // V at packed col 4096+
  }
  krep[((size_t)t * HL + hl) * D + d] = sum * 0.125f;
  uint4 pk;
  pk.x = pk2(vv[0], vv[1]);
  pk.y = pk2(vv[2], vv[3]);
  pk.z = pk2(vv[4], vv[5]);
  pk.w = pk2(vv[6], vv[7]);
  *(uint4*)(vbt + ((size_t)hl * D + d) * S + t * 8) = pk;
}

// ---------------- scores + top-100 selection per head -----------------------
__global__ __launch_bounds__(512) void topk_kernel(
    const float* __restrict__ M1, const float* __restrict__ M2,
    const float* __restrict__ krep, int* __restrict__ bidx) {
  const int h = blockIdx.x;
  const int t = threadIdx.x;  // block id 0..511
  __shared__ float qm[128];
  if (t < 128) {
    int r = h * 128 + t;
    float v = (t & 1) ? (M1[r] + M2[r - 1]) : (M1[r] - M2[r + 1]);
    qm[t] = v * (1.f / 4096.f);
  }
  __syncthreads();
  const float* kr = krep + ((size_t)t * HL + (h >> 2)) * 128;
  float s = 0.f;
#pragma unroll 8
  for (int d = 0; d < 128; ++d) s += qm[d] * kr[d];
  s *= SCALE;
  if (t < 4 || t >= 508) s = NEGF;  // sink + window masked out of top-k
  if (t < 4) {
    bidx[h * KL + t] = t;            // sink blocks 0..3
    bidx[h * KL + 4 + t] = 508 + t;  // window blocks 508..511
  }
  __shared__ float wv[8];
  __shared__ int wi[8];
  __shared__ int bestsh;
  for (int iter = 0; iter < 100; ++iter) {
    float v = s;
    int idx = t;
#pragma unroll
    for (int off = 1; off < 64; off <<= 1) {
      float ov = __shfl_xor(v, off, 64);
      int oi = __shfl_xor(idx, off, 64);
      if (ov > v || (ov == v && oi < idx)) { v = ov; idx = oi; }
    }
    if ((t & 63) == 0) { wv[t >> 6] = v; wi[t >> 6] = idx; }
    __syncthreads();
    if (t == 0) {
      float bv = wv[0];
      int bi = wi[0];
#pragma unroll
      for (int u = 1; u < 8; ++u)
        if (wv[u] > bv || (wv[u] == bv && wi[u] < bi)) { bv = wv[u]; bi = wi[u]; }
      bestsh = bi;
      bidx[h * KL + 8 + iter] = bi;
    }
    __syncthreads();
    if (t == bestsh) s = NEGF;
  }
}

// ---------------- MFMA flash attention over selected blocks -----------------
// 4 waves x 16 q-rows; KVBLK=64 (8 blocks/step, 14 steps); direct load->store
// LDS staging (round-6 structure, no persistent staging regs -> no scratch);
// T2 XOR-swizzle on Ks/Vt/Ps (chunk ^= row&7, write+read both sides —
// index math verified correct in round 7); defer-max rescale THR=8 (T13).
// LDS 40 KB -> 4 blocks/CU.
__global__ __launch_bounds__(256) void attn_mfma(
    const u16* __restrict__ qb, const u16* __restrict__ kb,
    const u16* __restrict__ vbt, const int* __restrict__ bidx,
    u16* __restrict__ attno) {
  __shared__ u16 Ks[64][128];   // [tok][d]   chunk-XOR swizzled, no pad
  __shared__ u16 Vt[128][64];   // [d][tok]   chunk-XOR swizzled, no pad
  __shared__ u16 Ps[4][16][64]; // [w][qrow][tok] chunk-XOR swizzled, no pad
  const int h = blockIdx.y, hl = h >> 2;
  const int q0 = blockIdx.x * 64;
  const int tid = threadIdx.x;
  const int w = tid >> 6, lane = tid & 63;
  const int l15 = lane & 15, g = lane >> 4;
  const int l7 = l15 & 7;
  constexpr int NS = (KL + 7) / 8;  // 14 (last step: 4 valid slots)

  bf16x8 qf[4];
  {
    const u16* qp = qb + ((size_t)h * S + q0 + w * 16 + l15) * D + g * 8;
#pragma unroll
    for (int c = 0; c < 4; ++c) qf[c] = *(const bf16x8*)(qp + c * 32);
  }
  f32x4 o[8];
#pragma unroll
  for (int c = 0; c < 8; ++c) o[c] = {0.f, 0.f, 0.f, 0.f};
  float mrow[4], lrow[4];
#pragma unroll
  for (int r = 0; r < 4; ++r) { mrow[r] = NEGF; lrow[r] = 0.f; }

  // staging roles (load -> immediate store; registers die right away)
  const int ktok = tid >> 2, kq = tid & 3;  // K: token row 0..63, 64B segment
  const int kx = ktok & 7;
  const int vd = tid >> 1, vh = tid & 1;    // V: d row 0..127, 4-block half
  const int vx = vd & 7;

  for (int t = 0; t < NS; ++t) {
    // token bases for masking (uniform scalar loads)
    int tb[8];
#pragma unroll
    for (int s = 0; s < 8; ++s) {
      const int st = t * 8 + s;
      tb[s] = (st < KL) ? bidx[h * KL + st] * 8 : S + 8;
    }
    {  // stage K: this thread's token row, 64B contiguous, swizzled chunks
      const int kslot = t * 8 + (ktok >> 3);
      const int kblk = (kslot < KL) ? bidx[h * KL + kslot] : 0;
      const u16* src = kb + ((size_t)hl * S + kblk * 8 + (ktok & 7)) * D + kq * 32;
#pragma unroll
      for (int j = 0; j < 4; ++j)
        *(uint4*)&Ks[ktok][((kq * 4 + j) ^ kx) * 8] = *(const uint4*)(src + j * 8);
    }
    {  // stage V^T: 4 blocks of this thread's half, swizzled chunks
      const u16* vsrc = vbt + ((size_t)hl * D + vd) * S;
#pragma unroll
      for (int j = 0; j < 4; ++j) {
        const int vslot = t * 8 + vh * 4 + j;
        const int vblk = (vslot < KL) ? bidx[h * KL + vslot] : 0;
        *(uint4*)&Vt[vd][((vh * 4 + j) ^ vx) * 8] = *(const uint4*)(vsrc + (size_t)vblk * 8);
      }
    }
    __syncthreads();

    // QK^T: 4 token-tiles x 4 d-chunks (swizzled reads)
    f32x4 sT[4];
#pragma unroll
    for (int ti = 0; ti < 4; ++ti) sT[ti] = {0.f, 0.f, 0.f, 0.f};
#pragma unroll
    for (int c = 0; c < 4; ++c)
#pragma unroll
      for (int ti = 0; ti < 4; ++ti) {
        bf16x8 kf = *(const bf16x8*)&Ks[ti * 16 + l15][((c * 4 + g) ^ l7) * 8];
        sT[ti] = __builtin_amdgcn_mfma_f32_16x16x32_bf16(qf[c], kf, sT[ti], 0, 0, 0);
      }

    // masks + per-row max
    int tg[4];
#pragma unroll
    for (int ti = 0; ti < 4; ++ti)
      tg[ti] = ((l15 & 8) ? tb[ti * 2 + 1] : tb[ti * 2]) + (l15 & 7);
    float p[4][4], mx[4];
#pragma unroll
    for (int r = 0; r < 4; ++r) {
      const int sq = q0 + w * 16 + g * 4 + r;
      float m = NEGF;
#pragma unroll
      for (int ti = 0; ti < 4; ++ti) {
        p[r][ti] = (tg[ti] <= sq) ? sT[ti][r] * SCALE : NEGF;
        m = fmaxf(m, p[r][ti]);
      }
      m = fmaxf(m, __shfl_xor(m, 1, 64));
      m = fmaxf(m, __shfl_xor(m, 2, 64));
      m = fmaxf(m, __shfl_xor(m, 4, 64));
      m = fmaxf(m, __shfl_xor(m, 8, 64));
      mx[r] = m;
    }
    // defer-max: rescale only if some row's max grew past THR=8
    const bool need = (mx[0] > mrow[0] + 8.f) | (mx[1] > mrow[1] + 8.f) |
                      (mx[2] > mrow[2] + 8.f) | (mx[3] > mrow[3] + 8.f);
    if (__any((int)need)) {
#pragma unroll
      for (int r = 0; r < 4; ++r) {
        const float mnew = fmaxf(mrow[r], mx[r]);
        const float alpha = __expf(mrow[r] - mnew);
        mrow[r] = mnew;
        lrow[r] *= alpha;
#pragma unroll
        for (int c = 0; c < 8; ++c) o[c][r] *= alpha;
      }
    }
    // exp + row-sum + P store (bounded by e^8 under defer; swizzled store)
#pragma unroll
    for (int r = 0; r < 4; ++r) {
      float rs = 0.f;
#pragma unroll
      for (int ti = 0; ti < 4; ++ti) {
        p[r][ti] = __expf(p[r][ti] - mrow[r]);
        rs += p[r][ti];
      }
      rs += __shfl_xor(rs, 1, 64);
      rs += __shfl_xor(rs, 2, 64);
      rs += __shfl_xor(rs, 4, 64);
      rs += __shfl_xor(rs, 8, 64);
      lrow[r] += rs;
      const int prow = g * 4 + r;
      const int px = prow & 7;
#pragma unroll
      for (int ti = 0; ti < 4; ++ti) {
        const int ch = ti * 2 + (l15 >> 3);          // logical 8-elem chunk
        Ps[w][prow][((ch ^ px) * 8) + l7] = rne16(p[r][ti]);
      }
    }
    // PV: K=64 via two 32-token chunks (swizzled reads)
    bf16x8 pf0 = *(const bf16x8*)&Ps[w][l15][(g ^ l7) * 8];
    bf16x8 pf1 = *(const bf16x8*)&Ps[w][l15][((4 + g) ^ l7) * 8];
#pragma unroll
    for (int c = 0; c < 8; ++c) {
      const int vrow = c * 16 + l15;
      bf16x8 v0 = *(const bf16x8*)&Vt[vrow][(g ^ l7) * 8];
      bf16x8 v1 = *(const bf16x8*)&Vt[vrow][((4 + g) ^ l7) * 8];
      o[c] = __builtin_amdgcn_mfma_f32_16x16x32_bf16(pf0, v0, o[c], 0, 0, 0);
      o[c] = __builtin_amdgcn_mfma_f32_16x16x32_bf16(pf1, v1, o[c], 0, 0, 0);
    }
    __syncthreads();          // all waves done with Ks/Vt before next staging
  }
  float inv[4];
#pragma unroll
  for (int r = 0; r < 4; ++r) inv[r] = 1.f / lrow[r];
#pragma unroll
  for (int c = 0; c < 8; ++c)
#pragma unroll
    for (int r = 0; r < 4; ++r)
      attno[(size_t)(q0 + w * 16 + g * 4 + r) * DIM + h * D + c * 16 + l15] =
          rne16(o[c][r] * inv[r]);
}

extern "C" void kernel_launch(void* const* d_in, const int* in_sizes, int n_in,
                              void* d_out, int out_size, void* d_ws, size_t ws_size,
                              hipStream_t stream) {
  const float* x     = (const float*)d_in[0];  // (1,4096,4096)
  const float* freqs = (const float*)d_in[1];  // (4096,64,2)
  const float* wqkv  = (const float*)d_in[2];  // (6144,4096)
  const float* wo    = (const float*)d_in[3];  // (4096,4096)
  float* out = (float*)d_out;                  // (1,4096,4096) f32

  char* p = (char*)d_ws;
  auto alloc = [&](size_t bytes) {
    char* r = p;
    p += (bytes + 255) & ~(size_t)255;
    return r;
  };
  u16*   xh   = (u16*)alloc((size_t)S * DIM * 2);        // 32 MB x hi (rne bf16)
  u16*   xl   = (u16*)alloc((size_t)S * DIM * 2);        // 32 MB x lo residual
  u16*   wqv  = (u16*)alloc((size_t)QVW * DIM * 2);      // 40 MB packed [Q|V] bf16
  u16*   wkh  = (u16*)alloc((size_t)HL * D * DIM * 2);   //  8 MB K-head hi
  u16*   wkl  = (u16*)alloc((size_t)HL * D * DIM * 2);   //  8 MB K-head lo
  u16*   wob  = (u16*)alloc((size_t)DIM * DIM * 2);      // 32 MB wo bf16
  u16*   qvb  = (u16*)alloc((size_t)S * QVW * 2);        // 40 MB bf16 [Q|V]
  float* kf32 = (float*)alloc((size_t)S * HL * D * 4);   // 16 MB precise k
  u16*   qb   = (u16*)alloc((size_t)H * S * D * 2);      // 32 MB (H,S,D)
  u16*   kb   = (u16*)alloc((size_t)HL * S * D * 2);     //  8 MB (HL,S,D)
  u16*   vbt  = (u16*)alloc((size_t)HL * D * S * 2);     //  8 MB (HL,D,S)
  float* krep = (float*)alloc((size_t)TB * HL * D * 4);  //  2 MB
  float* XC   = (float*)alloc((size_t)64 * DIM * 4);     //  1 MB
  float* XD   = (float*)alloc((size_t)64 * DIM * 4);     //  1 MB
  float* M1   = (float*)alloc((size_t)H * D * 4);
  float* M2   = (float*)alloc((size_t)H * D * 4);
  int*   bidx = (int*)alloc((size_t)H * KL * 4);
  u16*   attno = (u16*)alloc((size_t)S * DIM * 2);       // 32 MB

  hipMemsetAsync(XC, 0, (size_t)64 * DIM * 4, stream);
  hipMemsetAsync(XD, 0, (size_t)64 * DIM * 4, stream);

  // ---- conversion passes (memory-bound) ----
  split_f32_kernel<<<(S * DIM) / 2048, 256, 0, stream>>>(x, xh, xl);
  conv_wqkv_kernel<<<(NQKV * DIM) / 2048, 256, 0, stream>>>(wqkv, wqv, wkh, wkl);
  cast_bf16_kernel<<<(DIM * DIM) / 2048, 256, 0, stream>>>(wo, wob);

  // ---- bf16 Q (8-phase 256^2; grid 256 = 1 block/CU) ----
  gemm256<true><<<dim3((H * D) / 256, S / 256), 512, 0, stream>>>(
      xh, wqv, qvb, S, H * D, DIM, DIM, DIM, QVW);
  // ---- bf16 V (2-phase 128^2; N=1024, grid 256) ----
  gemm_bf16<true><<<dim3((HL * D) / 128, S / 128), 256, 0, stream>>>(
      xh, wqv + (size_t)(H * D) * DIM, qvb + H * D, S, HL * D, DIM, DIM, DIM, QVW);

  // ---- precise K heads: fused (Al*Bh + Ah*Bl + Ah*Bh), single pass ----
  gemm_k3<<<dim3((HL * D) / 64, S / 128), 256, 0, stream>>>(
      xh, xl, wkh, wkl, kf32, S, HL * D, DIM);

  // ---- exact q_mean via rope linearity (f32 inputs, unchanged) ----
  xcd_kernel<<<dim3(32, 2, 32), 128, 0, stream>>>(x, freqs, XC, XD);
  mrow_kernel<<<1024, 256, 0, stream>>>(wqkv, XC, XD, M1, M2);
  rope_q_kernel<<<dim3(S / 64, H), 256, 0, stream>>>(qvb, freqs, qb);
  rope_kv_kernel<<<dim3(TB, HL), 128, 0, stream>>>(kf32, qvb, freqs, kb, vbt, krep);
  topk_kernel<<<H, 512, 0, stream>>>(M1, M2, krep, bidx);
  attn_mfma<<<dim3(S / 64, H), 256, 0, stream>>>(qb, kb, vbt, bidx, attno);
  // ---- output projection (8-phase 256^2; grid 256) ----
  gemm256<false><<<dim3(DIM / 256, S / 256), 512, 0, stream>>>(
      attno, wob, out, S, DIM, DIM, DIM, DIM, DIM);
}

// Round 9
// 1272.713 us; speedup vs baseline: 1.1021x; 1.0175x over previous
//
#include <hip/hip_runtime.h>
#include <hip/hip_bf16.h>

typedef unsigned short u16;
typedef unsigned int   u32;

using bf16x8 = __attribute__((ext_vector_type(8))) short;
using f32x4  = __attribute__((ext_vector_type(4))) float;

constexpr int S = 4096, DIM = 4096, H = 32, HL = 8, D = 128;
constexpr int NQKV = (H + 2 * HL) * D;   // 6144
constexpr int QVW = (H + HL) * D;        // 5120: packed [Q | V] width
constexpr int TB = S / 8;                // 512 blocks of 8 tokens
constexpr int KL = 108;                  // 4 sink + 4 window + 100 heavy
constexpr float NEGF = -1e30f;
constexpr float SCALE = 0.08838834764831845f;  // 1/sqrt(128)

__device__ inline float bflo(u32 u) { return __builtin_bit_cast(float, u << 16); }
__device__ inline float bfhi(u32 u) { return __builtin_bit_cast(float, u & 0xFFFF0000u); }
__device__ inline u16 rne16(float f) {
  u32 b = __builtin_bit_cast(u32, f);
  return (u16)((b + 0x7FFFu + ((b >> 16) & 1u)) >> 16);
}
__device__ inline float bf2f(u16 h) { return __builtin_bit_cast(float, (u32)h << 16); }
__device__ inline u32 pk2(u16 a, u16 b) { return (u32)a | ((u32)b << 16); }

// async global->LDS, 16B per lane. LDS dest = wave-uniform base + lane*16.
__device__ __forceinline__ void gload16(const u16* g, u16* l) {
  __builtin_amdgcn_global_load_lds(
      (__attribute__((address_space(1))) void*)g,
      (__attribute__((address_space(3))) void*)l, 16, 0, 0);
}

// bijective XCD-aware swizzle of the flat workgroup id (nwg % 8 == 0).
__device__ inline void xcd_swz(int nx, int& bx, int& by) {
  const int flat = blockIdx.y * nx + blockIdx.x;
  const int nwg = nx * gridDim.y;
  const int cpx = nwg >> 3;
  const int s = (flat & 7) * cpx + (flat >> 3);
  bx = s % nx;
  by = s / nx;
}

// ================= conversion passes (memory-bound, one-shot) ===============
__global__ __launch_bounds__(256) void split_f32_kernel(
    const float* __restrict__ src, u16* __restrict__ hi, u16* __restrict__ lo) {
  const size_t i = ((size_t)blockIdx.x * 256 + threadIdx.x) * 8;
  float4 v0 = *(const float4*)(src + i);
  float4 v1 = *(const float4*)(src + i + 4);
  float f[8] = {v0.x, v0.y, v0.z, v0.w, v1.x, v1.y, v1.z, v1.w};
  u16 h[8], l[8];
#pragma unroll
  for (int j = 0; j < 8; ++j) {
    h[j] = rne16(f[j]);
    l[j] = rne16(f[j] - bf2f(h[j]));
  }
  uint4 ph, pl;
  ph.x = pk2(h[0], h[1]); ph.y = pk2(h[2], h[3]);
  ph.z = pk2(h[4], h[5]); ph.w = pk2(h[6], h[7]);
  pl.x = pk2(l[0], l[1]); pl.y = pk2(l[2], l[3]);
  pl.z = pk2(l[4], l[5]); pl.w = pk2(l[6], l[7]);
  *(uint4*)(hi + i) = ph;
  *(uint4*)(lo + i) = pl;
}

// wqkv f32 -> packed bf16 [Q rows | V rows] + K-head hi/lo separate buffers.
__global__ __launch_bounds__(256) void conv_wqkv_kernel(
    const float* __restrict__ src, u16* __restrict__ wqv,
    u16* __restrict__ wkh, u16* __restrict__ wkl) {
  const size_t i = ((size_t)blockIdx.x * 256 + threadIdx.x) * 8;
  float4 v0 = *(const float4*)(src + i);
  float4 v1 = *(const float4*)(src + i + 4);
  float f[8] = {v0.x, v0.y, v0.z, v0.w, v1.x, v1.y, v1.z, v1.w};
  u16 h[8];
#pragma unroll
  for (int j = 0; j < 8; ++j) h[j] = rne16(f[j]);
  uint4 ph;
  ph.x = pk2(h[0], h[1]); ph.y = pk2(h[2], h[3]);
  ph.z = pk2(h[4], h[5]); ph.w = pk2(h[6], h[7]);
  const int row = (int)(i >> 12);
  if (row < H * D) {                       // Q rows -> wqv[0..4095]
    *(uint4*)(wqv + i) = ph;
  } else if (row < (H + HL) * D) {         // K rows -> wkh/wkl
    const size_t off = i - (size_t)(H * D) * DIM;
    u16 l[8];
#pragma unroll
    for (int j = 0; j < 8; ++j) l[j] = rne16(f[j] - bf2f(h[j]));
    uint4 pl;
    pl.x = pk2(l[0], l[1]); pl.y = pk2(l[2], l[3]);
    pl.z = pk2(l[4], l[5]); pl.w = pk2(l[6], l[7]);
    *(uint4*)(wkh + off) = ph;
    *(uint4*)(wkl + off) = pl;
  } else {                                 // V rows -> wqv[4096..5119]
    *(uint4*)(wqv + (i - (size_t)(HL * D) * DIM)) = ph;
  }
}

__global__ __launch_bounds__(256) void cast_bf16_kernel(
    const float* __restrict__ src, u16* __restrict__ dst) {
  const size_t i = ((size_t)blockIdx.x * 256 + threadIdx.x) * 8;
  float4 v0 = *(const float4*)(src + i);
  float4 v1 = *(const float4*)(src + i + 4);
  uint4 ph;
  ph.x = pk2(rne16(v0.x), rne16(v0.y));
  ph.y = pk2(rne16(v0.z), rne16(v0.w));
  ph.z = pk2(rne16(v1.x), rne16(v1.y));
  ph.w = pk2(rne16(v1.z), rne16(v1.w));
  *(uint4*)(dst + i) = ph;
}

// ============ 8-phase 256x256 bf16 GEMM: C[M,N] = A[M,K] * B[N,K]^T =========
// v2: template-faithful phase shape — per phase {ds_read this phase's frags
// || stage issue} -> s_barrier -> lgkmcnt(0)+sched_barrier -> setprio MFMA
// -> s_barrier. Inter-barrier MFMA region is pure matrix work; LDS latency
// overlaps barrier skew. Drain of tile t+1's stages at t-ph3 (2-3 phases
// after issue -> wait~0), published by ph3's barriers before t+1-ph0 reads.
template <bool OBF16>
__global__ __launch_bounds__(512, 2) void gemm256(
    const u16* __restrict__ A, const u16* __restrict__ B,
    void* __restrict__ Cp, int M, int N, int K, int lda, int ldb, int ldc) {
  __shared__ u16 lds[4 * 16384];  // [buf][A|B][256*64]
  const int tid = threadIdx.x;
  const int w = tid >> 6, lane = tid & 63;
  const int wm = w >> 2, wn = w & 3;          // 2 x 4 wave grid
  const int l15 = lane & 15, g = lane >> 4;
  int bx, by;
  xcd_swz(gridDim.x, bx, by);
  const int m0 = by * 256, n0 = bx * 256;

  const u16* ga[4];
  const u16* gb[4];
#pragma unroll
  for (int r = 0; r < 4; ++r) {
    const int c = r * 512 + tid;
    const int row = c >> 3, j = c & 7;
    const int jsw = j ^ (row & 7);
    ga[r] = A + (size_t)(m0 + row) * lda + jsw * 8;
    gb[r] = B + (size_t)(n0 + row) * ldb + jsw * 8;
  }

  auto stageA = [&](int buf, int kt) {
    u16* base = lds + buf * 32768 + w * 512;
#pragma unroll
    for (int r = 0; r < 4; ++r) gload16(ga[r] + kt * 64, base + r * 4096);
  };
  auto stageB = [&](int buf, int kt) {
    u16* base = lds + buf * 32768 + 16384 + w * 512;
#pragma unroll
    for (int r = 0; r < 4; ++r) gload16(gb[r] + kt * 64, base + r * 4096);
  };

  bf16x8 afr[4][2], bfr[2][2];
  auto loadA = [&](int buf, int q) {
    const u16* Ab = lds + buf * 32768;
#pragma unroll
    for (int fr = 0; fr < 4; ++fr) {
      const int row = wm * 128 + q * 64 + fr * 16 + l15;
#pragma unroll
      for (int kh = 0; kh < 2; ++kh)
        afr[fr][kh] = *(const bf16x8*)(Ab + row * 64 + ((((kh << 2) | g)) ^ (l15 & 7)) * 8);
    }
  };
  auto loadB = [&](int buf, int r2) {
    const u16* Bb = lds + buf * 32768 + 16384;
#pragma unroll
    for (int fc = 0; fc < 2; ++fc) {
      const int row = wn * 64 + r2 * 32 + fc * 16 + l15;
#pragma unroll
      for (int kh = 0; kh < 2; ++kh)
        bfr[fc][kh] = *(const bf16x8*)(Bb + row * 64 + ((((kh << 2) | g)) ^ (l15 & 7)) * 8);
    }
  };

  f32x4 acc[8][4];
#pragma unroll
  for (int i = 0; i < 8; ++i)
#pragma unroll
    for (int j = 0; j < 4; ++j) acc[i][j] = {0.f, 0.f, 0.f, 0.f};

  auto mma = [&](int q, int r2) {
    asm volatile("s_waitcnt lgkmcnt(0)" ::: "memory");
    __builtin_amdgcn_sched_barrier(0);
    __builtin_amdgcn_s_setprio(1);
#pragma unroll
    for (int fr = 0; fr < 4; ++fr)
#pragma unroll
      for (int fc = 0; fc < 2; ++fc)
#pragma unroll
        for (int kh = 0; kh < 2; ++kh)
          acc[q * 4 + fr][r2 * 2 + fc] = __builtin_amdgcn_mfma_f32_16x16x32_bf16(
              afr[fr][kh], bfr[fc][kh], acc[q * 4 + fr][r2 * 2 + fc], 0, 0, 0);
    __builtin_amdgcn_s_setprio(0);
  };

  // prologue: stage tile 0, drain, publish.
  stageA(0, 0);
  stageB(0, 0);
  asm volatile("s_waitcnt vmcnt(0)" ::: "memory");
  __builtin_amdgcn_s_barrier();

  const int NT = K / 64;
  for (int t = 0; t < NT; ++t) {
    const int cur = t & 1, nxt = cur ^ 1;
    const bool hasNext = (t + 1 < NT);
    // ---- ph0: ds_read Q(0,0) frags || stage A(t+1) ----
    loadA(cur, 0);
    loadB(cur, 0);
    if (hasNext) stageA(nxt, t + 1);
    __builtin_amdgcn_s_barrier();
    mma(0, 0);
    __builtin_amdgcn_s_barrier();
    // ---- ph1: ds_read A(q=1) (B frags kept) || stage B(t+1) ----
    loadA(cur, 1);
    if (hasNext) stageB(nxt, t + 1);
    __builtin_amdgcn_s_barrier();
    mma(1, 0);
    __builtin_amdgcn_s_barrier();
    // ---- ph2: ds_read Q(0,1) frags ----
    loadA(cur, 0);
    loadB(cur, 1);
    __builtin_amdgcn_s_barrier();
    mma(0, 1);
    __builtin_amdgcn_s_barrier();
    // ---- ph3: ds_read A(q=1); drain t+1's stages (issued 2-3 phases ago,
    //      wait ~0); ph3's two barriers publish before t+1-ph0 reads ----
    loadA(cur, 1);
    if (hasNext) asm volatile("s_waitcnt vmcnt(0)" ::: "memory");
    __builtin_amdgcn_s_barrier();
    mma(1, 1);
    __builtin_amdgcn_s_barrier();
  }
  // C/D layout: col = lane&15, row = (lane>>4)*4 + reg   [verified m89/m91]
#pragma unroll
  for (int mf = 0; mf < 8; ++mf)
#pragma unroll
    for (int nf = 0; nf < 4; ++nf)
#pragma unroll
      for (int rg = 0; rg < 4; ++rg) {
        const int row = m0 + wm * 128 + mf * 16 + g * 4 + rg;
        const int col = n0 + wn * 64 + nf * 16 + l15;
        if constexpr (OBF16)
          ((u16*)Cp)[(size_t)row * ldc + col] = rne16(acc[mf][nf][rg]);
        else
          ((float*)Cp)[(size_t)row * ldc + col] = acc[mf][nf][rg];
      }
}

// ============ bf16 GEMM, 2-phase 128x128 (kept for the small V GEMM) ========
template <bool OBF16>
__global__ __launch_bounds__(256) void gemm_bf16(
    const u16* __restrict__ A, const u16* __restrict__ B,
    void* __restrict__ Cp, int M, int N, int K, int lda, int ldb, int ldc) {
  __shared__ u16 As[2][128 * 32];
  __shared__ u16 Bs[2][128 * 32];
  const int tid = threadIdx.x;
  const int lane = tid & 63;
  const int w = tid >> 6;
  const int wm = w >> 1, wn = w & 1;
  int bx, by;
  xcd_swz(gridDim.x, bx, by);
  const int m0 = by * 128, n0 = bx * 128;
  const int l15 = lane & 15, g = lane >> 4;
  const int srow = tid >> 2;          // 0..63
  const int scol = (tid & 3) * 8;     // u16 units: 0,8,16,24

  const u16* ga = A + (size_t)(m0 + srow) * lda + scol;
  const u16* gb = B + (size_t)(n0 + srow) * ldb + scol;
  const size_t a64 = (size_t)64 * lda;
  const size_t b64 = (size_t)64 * ldb;

  auto stage = [&](int buf, int k0) {
    u16* lA = As[buf] + w * 512;      // 1024 B per wave
    u16* lB = Bs[buf] + w * 512;
    gload16(ga + k0, lA);             // A rows 0..63
    gload16(ga + k0 + a64, lA + 2048);// A rows 64..127
    gload16(gb + k0, lB);             // B rows 0..63
    gload16(gb + k0 + b64, lB + 2048);// B rows 64..127
  };

  f32x4 acc[4][4];
#pragma unroll
  for (int i = 0; i < 4; ++i)
#pragma unroll
    for (int j = 0; j < 4; ++j) acc[i][j] = {0.f, 0.f, 0.f, 0.f};

  stage(0, 0);
  __syncthreads();
  const int niter = K / 32;
  for (int it = 0; it < niter; ++it) {
    const int cur = it & 1;
    if (it + 1 < niter) stage(cur ^ 1, (it + 1) * 32);  // prefetch in flight
    bf16x8 af[4], bfr[4];
#pragma unroll
    for (int i = 0; i < 4; ++i)
      af[i] = *(const bf16x8*)(As[cur] + (wm * 64 + i * 16 + l15) * 32 + g * 8);
#pragma unroll
    for (int j = 0; j < 4; ++j)
      bfr[j] = *(const bf16x8*)(Bs[cur] + (wn * 64 + j * 16 + l15) * 32 + g * 8);
#pragma unroll
    for (int i = 0; i < 4; ++i)
#pragma unroll
      for (int j = 0; j < 4; ++j)
        acc[i][j] = __builtin_amdgcn_mfma_f32_16x16x32_bf16(af[i], bfr[j], acc[i][j], 0, 0, 0);
    __syncthreads();  // drains prefetch (hidden behind MFMA) + barrier
  }
#pragma unroll
  for (int i = 0; i < 4; ++i)
#pragma unroll
    for (int j = 0; j < 4; ++j)
#pragma unroll
      for (int rg = 0; rg < 4; ++rg) {
        const int row = m0 + wm * 64 + i * 16 + g * 4 + rg;
        const int col = n0 + wn * 64 + j * 16 + l15;
        if constexpr (OBF16)
          ((u16*)Cp)[(size_t)row * ldc + col] = rne16(acc[i][j][rg]);
        else
          ((float*)Cp)[(size_t)row * ldc + col] = acc[i][j][rg];
      }
}

// ============ fused 3-term split GEMM: C = Al*Bh^T + Ah*Bl^T + Ah*Bh^T ======
__global__ __launch_bounds__(256) void gemm_k3(
    const u16* __restrict__ Ahg, const u16* __restrict__ Alg,
    const u16* __restrict__ Bhg, const u16* __restrict__ Blg,
    float* __restrict__ C, int M, int N, int K) {
  __shared__ u16 Ah[2][128 * 32];
  __shared__ u16 Al[2][128 * 32];
  __shared__ u16 Bh[2][64 * 32];
  __shared__ u16 Bl[2][64 * 32];
  const int tid = threadIdx.x;
  const int lane = tid & 63;
  const int w = tid >> 6;
  const int wm = w >> 1, wn = w & 1;   // wave tile: 64(M) x 32(N)
  int bx, by;
  xcd_swz(gridDim.x, bx, by);
  const int m0 = by * 128, n0 = bx * 64;
  const int l15 = lane & 15, g = lane >> 4;
  const int srow = tid >> 2;           // 0..63
  const int scol = (tid & 3) * 8;

  const u16* gah = Ahg + (size_t)(m0 + srow) * K + scol;
  const u16* gal = Alg + (size_t)(m0 + srow) * K + scol;
  const u16* gbh = Bhg + (size_t)(n0 + srow) * K + scol;
  const u16* gbl = Blg + (size_t)(n0 + srow) * K + scol;
  const size_t a64 = (size_t)64 * K;

  auto stage = [&](int buf, int k0) {
    gload16(gah + k0, Ah[buf] + w * 512);
    gload16(gah + k0 + a64, Ah[buf] + w * 512 + 2048);
    gload16(gal + k0, Al[buf] + w * 512);
    gload16(gal + k0 + a64, Al[buf] + w * 512 + 2048);
    gload16(gbh + k0, Bh[buf] + w * 512);
    gload16(gbl + k0, Bl[buf] + w * 512);
  };

  f32x4 acc[4][2];
#pragma unroll
  for (int i = 0; i < 4; ++i)
#pragma unroll
    for (int j = 0; j < 2; ++j) acc[i][j] = {0.f, 0.f, 0.f, 0.f};

  stage(0, 0);
  __syncthreads();
  const int niter = K / 32;
  for (int it = 0; it < niter; ++it) {
    const int cur = it & 1;
    if (it + 1 < niter) stage(cur ^ 1, (it + 1) * 32);
    bf16x8 fah[4], fal[4], fbh[2], fbl[2];
#pragma unroll
    for (int i = 0; i < 4; ++i) {
      fah[i] = *(const bf16x8*)(Ah[cur] + (wm * 64 + i * 16 + l15) * 32 + g * 8);
      fal[i] = *(const bf16x8*)(Al[cur] + (wm * 64 + i * 16 + l15) * 32 + g * 8);
    }
#pragma unroll
    for (int j = 0; j < 2; ++j) {
      fbh[j] = *(const bf16x8*)(Bh[cur] + (wn * 32 + j * 16 + l15) * 32 + g * 8);
      fbl[j] = *(const bf16x8*)(Bl[cur] + (wn * 32 + j * 16 + l15) * 32 + g * 8);
    }
#pragma unroll
    for (int i = 0; i < 4; ++i)
#pragma unroll
      for (int j = 0; j < 2; ++j) {
        acc[i][j] = __builtin_amdgcn_mfma_f32_16x16x32_bf16(fal[i], fbh[j], acc[i][j], 0, 0, 0);
        acc[i][j] = __builtin_amdgcn_mfma_f32_16x16x32_bf16(fah[i], fbl[j], acc[i][j], 0, 0, 0);
        acc[i][j] = __builtin_amdgcn_mfma_f32_16x16x32_bf16(fah[i], fbh[j], acc[i][j], 0, 0, 0);
      }
    __syncthreads();
  }
#pragma unroll
  for (int i = 0; i < 4; ++i)
#pragma unroll
    for (int j = 0; j < 2; ++j)
#pragma unroll
      for (int rg = 0; rg < 4; ++rg) {
        const int row = m0 + wm * 64 + i * 16 + g * 4 + rg;
        const int col = n0 + wn * 32 + j * 16 + l15;
        C[(size_t)row * N + col] = acc[i][j][rg];
      }
}

// ---------------- XC/XD: weighted token-sums of x (exact q_mean path) -------
__global__ __launch_bounds__(128) void xcd_kernel(
    const float* __restrict__ x, const float* __restrict__ freqs,
    float* __restrict__ XC, float* __restrict__ XD) {
  const int d = blockIdx.x * 128 + threadIdx.x;
  const int i0 = blockIdx.y * 32;
  const int s0 = blockIdx.z * 128;
  float accC[32], accD[32];
#pragma unroll
  for (int ii = 0; ii < 32; ++ii) { accC[ii] = 0.f; accD[ii] = 0.f; }
  for (int s = s0; s < s0 + 128; ++s) {
    const float xv = x[(size_t)s * DIM + d];
    const float* fr = freqs + (size_t)s * 128 + i0 * 2;  // block-uniform -> s_loads
#pragma unroll
    for (int ii = 0; ii < 32; ++ii) {
      accC[ii] += fr[2 * ii] * xv;
      accD[ii] += fr[2 * ii + 1] * xv;
    }
  }
#pragma unroll
  for (int ii = 0; ii < 32; ++ii) {
    atomicAdd(&XC[(size_t)(i0 + ii) * DIM + d], accC[ii]);
    atomicAdd(&XD[(size_t)(i0 + ii) * DIM + d], accD[ii]);
  }
}

// ---------------- M1/M2: per-q-row dots with XC/XD --------------------------
__global__ __launch_bounds__(256) void mrow_kernel(
    const float* __restrict__ wq, const float* __restrict__ XC,
    const float* __restrict__ XD, float* __restrict__ M1, float* __restrict__ M2) {
  const int r = blockIdx.x * 4 + (threadIdx.x >> 6);
  const int lane = threadIdx.x & 63;
  const int i = (r & 127) >> 1;
  const float* wr = wq + (size_t)r * DIM;
  const float* xc = XC + (size_t)i * DIM;
  const float* xd = XD + (size_t)i * DIM;
  float s1 = 0.f, s2 = 0.f;
  for (int k = lane; k < DIM; k += 64) {
    float wv = wr[k];
    s1 += wv * xc[k];
    s2 += wv * xd[k];
  }
#pragma unroll
  for (int off = 1; off < 64; off <<= 1) {
    s1 += __shfl_xor(s1, off, 64);
    s2 += __shfl_xor(s2, off, 64);
  }
  if (lane == 0) { M1[r] = s1; M2[r] = s2; }
}

// ---------------- RoPE on Q (bf16 in, bf16 out) -----------------------------
__global__ __launch_bounds__(256) void rope_q_kernel(
    const u16* __restrict__ qvb, const float* __restrict__ freqs,
    u16* __restrict__ qb) {
  const int h = blockIdx.y;
  const int s0 = blockIdx.x * 64;
  const int tid = threadIdx.x;
  const int d = tid & 127, half = tid >> 7;
  for (int pp = half; pp < 64; pp += 2) {
    const int s = s0 + pp;
    u32 pr = *(const u32*)(qvb + (size_t)s * QVW + h * D + (d & ~1));
    float a = bflo(pr), b = bfhi(pr);
    float2 fc = *(const float2*)(freqs + (size_t)s * 128 + (d & ~1));
    float o = (d & 1) ? (b * fc.x + a * fc.y) : (a * fc.x - b * fc.y);
    qb[((size_t)h * S + s) * D + d] = rne16(o);
  }
}

// ---------------- RoPE on precise K + block means; V cast + transpose -------
__global__ __launch_bounds__(128) void rope_kv_kernel(
    const float* __restrict__ kf, const u16* __restrict__ qvb,
    const float* __restrict__ freqs,
    u16* __restrict__ kb, u16* __restrict__ vbt, float* __restrict__ krep) {
  const int hl = blockIdx.y;
  const int t = blockIdx.x;  // token block 0..511
  const int d = threadIdx.x;
  float sum = 0.f;
  u16 vv[8];
#pragma unroll
  for (int pp = 0; pp < 8; ++pp) {
    const int s = t * 8 + pp;
    float2 kp = *(const float2*)(kf + (size_t)s * 1024 + hl * D + (d & ~1));
    float2 fc = *(const float2*)(freqs + (size_t)s * 128 + (d & ~1));
    float o = (d & 1) ? (kp.y * fc.x + kp.x * fc.y) : (kp.x * fc.x - kp.y * fc.y);
    kb[((size_t)hl * S + s) * D + d] = rne16(o);
    sum += o;
    vv[pp] = qvb[(size_t)s * QVW + H * D + hl * D + d];  // V at packed col 4096+
  }
  krep[((size_t)t * HL + hl) * D + d] = sum * 0.125f;
  uint4 pk;
  pk.x = pk2(vv[0], vv[1]);
  pk.y = pk2(vv[2], vv[3]);
  pk.z = pk2(vv[4], vv[5]);
  pk.w = pk2(vv[6], vv[7]);
  *(uint4*)(vbt + ((size_t)hl * D + d) * S + t * 8) = pk;
}

// ---------------- scores + top-100 selection per head -----------------------
__global__ __launch_bounds__(512) void topk_kernel(
    const float* __restrict__ M1, const float* __restrict__ M2,
    const float* __restrict__ krep, int* __restrict__ bidx) {
  const int h = blockIdx.x;
  const int t = threadIdx.x;  // block id 0..511
  __shared__ float qm[128];
  if (t < 128) {
    int r = h * 128 + t;
    float v = (t & 1) ? (M1[r] + M2[r - 1]) : (M1[r] - M2[r + 1]);
    qm[t] = v * (1.f / 4096.f);
  }
  __syncthreads();
  const float* kr = krep + ((size_t)t * HL + (h >> 2)) * 128;
  float s = 0.f;
#pragma unroll 8
  for (int d = 0; d < 128; ++d) s += qm[d] * kr[d];
  s *= SCALE;
  if (t < 4 || t >= 508) s = NEGF;  // sink + window masked out of top-k
  if (t < 4) {
    bidx[h * KL + t] = t;            // sink blocks 0..3
    bidx[h * KL + 4 + t] = 508 + t;  // window blocks 508..511
  }
  __shared__ float wv[8];
  __shared__ int wi[8];
  __shared__ int bestsh;
  for (int iter = 0; iter < 100; ++iter) {
    float v = s;
    int idx = t;
#pragma unroll
    for (int off = 1; off < 64; off <<= 1) {
      float ov = __shfl_xor(v, off, 64);
      int oi = __shfl_xor(idx, off, 64);
      if (ov > v || (ov == v && oi < idx)) { v = ov; idx = oi; }
    }
    if ((t & 63) == 0) { wv[t >> 6] = v; wi[t >> 6] = idx; }
    __syncthreads();
    if (t == 0) {
      float bv = wv[0];
      int bi = wi[0];
#pragma unroll
      for (int u = 1; u < 8; ++u)
        if (wv[u] > bv || (wv[u] == bv && wi[u] < bi)) { bv = wv[u]; bi = wi[u]; }
      bestsh = bi;
      bidx[h * KL + 8 + iter] = bi;
    }
    __syncthreads();
    if (t == bestsh) s = NEGF;
  }
}

// ---------------- MFMA flash attention over selected blocks -----------------
// 4 waves x 16 q-rows; KVBLK=64 (8 selected blocks/step, 14 steps);
// direct load->store LDS staging (no persistent staging regs -> no spill);
// defer-max rescale THR=8 (T13). [round-6 verified version, 228us]
__global__ __launch_bounds__(256) void attn_mfma(
    const u16* __restrict__ qb, const u16* __restrict__ kb,
    const u16* __restrict__ vbt, const int* __restrict__ bidx,
    u16* __restrict__ attno) {
  __shared__ u16 Ks[64][136];   // 64 toks x 128 d (+8 pad)
  __shared__ u16 Vt[128][72];   // 128 d x 64 toks (+8 pad)
  __shared__ u16 Ps[4][16][72]; // per wave: 16 rows x 64 toks (+8 pad)
  const int h = blockIdx.y, hl = h >> 2;
  const int q0 = blockIdx.x * 64;
  const int tid = threadIdx.x;
  const int w = tid >> 6, lane = tid & 63;
  const int l15 = lane & 15, g = lane >> 4;
  constexpr int NS = (KL + 7) / 8;  // 14 (last step: 4 valid slots)

  bf16x8 qf[4];
  {
    const u16* qp = qb + ((size_t)h * S + q0 + w * 16 + l15) * D + g * 8;
#pragma unroll
    for (int c = 0; c < 4; ++c) qf[c] = *(const bf16x8*)(qp + c * 32);
  }
  f32x4 o[8];
#pragma unroll
  for (int c = 0; c < 8; ++c) o[c] = {0.f, 0.f, 0.f, 0.f};
  float mrow[4], lrow[4];
#pragma unroll
  for (int r = 0; r < 4; ++r) { mrow[r] = NEGF; lrow[r] = 0.f; }

  // staging roles (load -> immediate store; registers die right away)
  const int ktok = tid >> 2, kq = tid & 3;  // K: token row 0..63, 64B segment
  const int vd = tid >> 1, vh = tid & 1;    // V: d row 0..127, 4-block half

  for (int t = 0; t < NS; ++t) {
    // token bases for masking (uniform scalar loads)
    int tb[8];
#pragma unroll
    for (int s = 0; s < 8; ++s) {
      const int st = t * 8 + s;
      tb[s] = (st < KL) ? bidx[h * KL + st] * 8 : S + 8;
    }
    {  // stage K: this thread's token row, 64B contiguous
      const int kslot = t * 8 + (ktok >> 3);
      const int kblk = (kslot < KL) ? bidx[h * KL + kslot] : 0;
      const u16* src = kb + ((size_t)hl * S + kblk * 8 + (ktok & 7)) * D + kq * 32;
      *(uint4*)&Ks[ktok][kq * 32] = *(const uint4*)src;
      *(uint4*)&Ks[ktok][kq * 32 + 8] = *(const uint4*)(src + 8);
      *(uint4*)&Ks[ktok][kq * 32 + 16] = *(const uint4*)(src + 16);
      *(uint4*)&Ks[ktok][kq * 32 + 24] = *(const uint4*)(src + 24);
    }
    {  // stage V^T: 4 blocks of this thread's half
      const u16* vsrc = vbt + ((size_t)hl * D + vd) * S;
#pragma unroll
      for (int j = 0; j < 4; ++j) {
        const int vslot = t * 8 + vh * 4 + j;
        const int vblk = (vslot < KL) ? bidx[h * KL + vslot] : 0;
        *(uint4*)&Vt[vd][vh * 32 + j * 8] = *(const uint4*)(vsrc + (size_t)vblk * 8);
      }
    }
    __syncthreads();

    // QK^T: 4 token-tiles x 4 d-chunks
    f32x4 sT[4];
#pragma unroll
    for (int ti = 0; ti < 4; ++ti) sT[ti] = {0.f, 0.f, 0.f, 0.f};
#pragma unroll
    for (int c = 0; c < 4; ++c)
#pragma unroll
      for (int ti = 0; ti < 4; ++ti) {
        bf16x8 kf = *(const bf16x8*)&Ks[ti * 16 + l15][c * 32 + g * 8];
        sT[ti] = __builtin_amdgcn_mfma_f32_16x16x32_bf16(qf[c], kf, sT[ti], 0, 0, 0);
      }

    // masks + per-row max
    int tg[4];
#pragma unroll
    for (int ti = 0; ti < 4; ++ti)
      tg[ti] = ((l15 & 8) ? tb[ti * 2 + 1] : tb[ti * 2]) + (l15 & 7);
    float p[4][4], mx[4];
#pragma unroll
    for (int r = 0; r < 4; ++r) {
      const int sq = q0 + w * 16 + g * 4 + r;
      float m = NEGF;
#pragma unroll
      for (int ti = 0; ti < 4; ++ti) {
        p[r][ti] = (tg[ti] <= sq) ? sT[ti][r] * SCALE : NEGF;
        m = fmaxf(m, p[r][ti]);
      }
      m = fmaxf(m, __shfl_xor(m, 1, 64));
      m = fmaxf(m, __shfl_xor(m, 2, 64));
      m = fmaxf(m, __shfl_xor(m, 4, 64));
      m = fmaxf(m, __shfl_xor(m, 8, 64));
      mx[r] = m;
    }
    // defer-max: rescale only if some row's max grew past THR=8
    const bool need = (mx[0] > mrow[0] + 8.f) | (mx[1] > mrow[1] + 8.f) |
                      (mx[2] > mrow[2] + 8.f) | (mx[3] > mrow[3] + 8.f);
    if (__any((int)need)) {
#pragma unroll
      for (int r = 0; r < 4; ++r) {
        const float mnew = fmaxf(mrow[r], mx[r]);
        const float alpha = __expf(mrow[r] - mnew);
        mrow[r] = mnew;
        lrow[r] *= alpha;
#pragma unroll
        for (int c = 0; c < 8; ++c) o[c][r] *= alpha;
      }
    }
    // exp + row-sum + P store (bounded by e^8 under defer)
#pragma unroll
    for (int r = 0; r < 4; ++r) {
      float rs = 0.f;
#pragma unroll
      for (int ti = 0; ti < 4; ++ti) {
        p[r][ti] = __expf(p[r][ti] - mrow[r]);
        rs += p[r][ti];
      }
      rs += __shfl_xor(rs, 1, 64);
      rs += __shfl_xor(rs, 2, 64);
      rs += __shfl_xor(rs, 4, 64);
      rs += __shfl_xor(rs, 8, 64);
      lrow[r] += rs;
#pragma unroll
      for (int ti = 0; ti < 4; ++ti)
        Ps[w][g * 4 + r][ti * 16 + l15] = rne16(p[r][ti]);
    }
    // PV: K=64 via two 32-token chunks
    bf16x8 pf0 = *(const bf16x8*)&Ps[w][l15][g * 8];
    bf16x8 pf1 = *(const bf16x8*)&Ps[w][l15][32 + g * 8];
#pragma unroll
    for (int c = 0; c < 8; ++c) {
      bf16x8 v0 = *(const bf16x8*)&Vt[c * 16 + l15][g * 8];
      bf16x8 v1 = *(const bf16x8*)&Vt[c * 16 + l15][32 + g * 8];
      o[c] = __builtin_amdgcn_mfma_f32_16x16x32_bf16(pf0, v0, o[c], 0, 0, 0);
      o[c] = __builtin_amdgcn_mfma_f32_16x16x32_bf16(pf1, v1, o[c], 0, 0, 0);
    }
    __syncthreads();          // all waves done with Ks/Vt before next staging
  }
  float inv[4];
#pragma unroll
  for (int r = 0; r < 4; ++r) inv[r] = 1.f / lrow[r];
#pragma unroll
  for (int c = 0; c < 8; ++c)
#pragma unroll
    for (int r = 0; r < 4; ++r)
      attno[(size_t)(q0 + w * 16 + g * 4 + r) * DIM + h * D + c * 16 + l15] =
          rne16(o[c][r] * inv[r]);
}

extern "C" void kernel_launch(void* const* d_in, const int* in_sizes, int n_in,
                              void* d_out, int out_size, void* d_ws, size_t ws_size,
                              hipStream_t stream) {
  const float* x     = (const float*)d_in[0];  // (1,4096,4096)
  const float* freqs = (const float*)d_in[1];  // (4096,64,2)
  const float* wqkv  = (const float*)d_in[2];  // (6144,4096)
  const float* wo    = (const float*)d_in[3];  // (4096,4096)
  float* out = (float*)d_out;                  // (1,4096,4096) f32

  char* p = (char*)d_ws;
  auto alloc = [&](size_t bytes) {
    char* r = p;
    p += (bytes + 255) & ~(size_t)255;
    return r;
  };
  u16*   xh   = (u16*)alloc((size_t)S * DIM * 2);        // 32 MB x hi (rne bf16)
  u16*   xl   = (u16*)alloc((size_t)S * DIM * 2);        // 32 MB x lo residual
  u16*   wqv  = (u16*)alloc((size_t)QVW * DIM * 2);      // 40 MB packed [Q|V] bf16
  u16*   wkh  = (u16*)alloc((size_t)HL * D * DIM * 2);   //  8 MB K-head hi
  u16*   wkl  = (u16*)alloc((size_t)HL * D * DIM * 2);   //  8 MB K-head lo
  u16*   wob  = (u16*)alloc((size_t)DIM * DIM * 2);      // 32 MB wo bf16
  u16*   qvb  = (u16*)alloc((size_t)S * QVW * 2);        // 40 MB bf16 [Q|V]
  float* kf32 = (float*)alloc((size_t)S * HL * D * 4);   // 16 MB precise k
  u16*   qb   = (u16*)alloc((size_t)H * S * D * 2);      // 32 MB (H,S,D)
  u16*   kb   = (u16*)alloc((size_t)HL * S * D * 2);     //  8 MB (HL,S,D)
  u16*   vbt  = (u16*)alloc((size_t)HL * D * S * 2);     //  8 MB (HL,D,S)
  float* krep = (float*)alloc((size_t)TB * HL * D * 4);  //  2 MB
  float* XC   = (float*)alloc((size_t)64 * DIM * 4);     //  1 MB
  float* XD   = (float*)alloc((size_t)64 * DIM * 4);     //  1 MB
  float* M1   = (float*)alloc((size_t)H * D * 4);
  float* M2   = (float*)alloc((size_t)H * D * 4);
  int*   bidx = (int*)alloc((size_t)H * KL * 4);
  u16*   attno = (u16*)alloc((size_t)S * DIM * 2);       // 32 MB

  hipMemsetAsync(XC, 0, (size_t)64 * DIM * 4, stream);
  hipMemsetAsync(XD, 0, (size_t)64 * DIM * 4, stream);

  // ---- conversion passes (memory-bound) ----
  split_f32_kernel<<<(S * DIM) / 2048, 256, 0, stream>>>(x, xh, xl);
  conv_wqkv_kernel<<<(NQKV * DIM) / 2048, 256, 0, stream>>>(wqkv, wqv, wkh, wkl);
  cast_bf16_kernel<<<(DIM * DIM) / 2048, 256, 0, stream>>>(wo, wob);

  // ---- bf16 Q (8-phase 256^2 v2; grid 256 = 1 block/CU) ----
  gemm256<true><<<dim3((H * D) / 256, S / 256), 512, 0, stream>>>(
      xh, wqv, qvb, S, H * D, DIM, DIM, DIM, QVW);
  // ---- bf16 V (2-phase 128^2; N=1024, grid 256) ----
  gemm_bf16<true><<<dim3((HL * D) / 128, S / 128), 256, 0, stream>>>(
      xh, wqv + (size_t)(H * D) * DIM, qvb + H * D, S, HL * D, DIM, DIM, DIM, QVW);

  // ---- precise K heads: fused (Al*Bh + Ah*Bl + Ah*Bh), single pass ----
  gemm_k3<<<dim3((HL * D) / 64, S / 128), 256, 0, stream>>>(
      xh, xl, wkh, wkl, kf32, S, HL * D, DIM);

  // ---- exact q_mean via rope linearity (f32 inputs, unchanged) ----
  xcd_kernel<<<dim3(32, 2, 32), 128, 0, stream>>>(x, freqs, XC, XD);
  mrow_kernel<<<1024, 256, 0, stream>>>(wqkv, XC, XD, M1, M2);
  rope_q_kernel<<<dim3(S / 64, H), 256, 0, stream>>>(qvb, freqs, qb);
  rope_kv_kernel<<<dim3(TB, HL), 128, 0, stream>>>(kf32, qvb, freqs, kb, vbt, krep);
  topk_kernel<<<H, 512, 0, stream>>>(M1, M2, krep, bidx);
  attn_mfma<<<dim3(S / 64, H), 256, 0, stream>>>(qb, kb, vbt, bidx, attno);
  // ---- output projection (8-phase 256^2 v2; grid 256) ----
  gemm256<false><<<dim3(DIM / 256, S / 256), 512, 0, stream>>>(
      attno, wob, out, S, DIM, DIM, DIM, DIM, DIM);
}